// Round 9
// baseline (1401.272 us; speedup 1.0000x reference)
//
#include <hip/hip_runtime.h>
#include <hip/hip_bf16.h>

#define B_ 16
#define S_ 2048
#define C_ 512
#define H_ 8192

#define LAMBDA_INIT_F 0.3555090675909693f
#define ONE_M_LI_F    0.6444909324090307f
#define SCALE_F       0.14865088937534013f

using bf16x8 = __attribute__((ext_vector_type(8))) short;
using f32x4  = __attribute__((ext_vector_type(4))) float;

__device__ __forceinline__ float b2f(ushort u) {
  union { unsigned u; float f; } x; x.u = ((unsigned)u) << 16; return x.f;
}
__device__ __forceinline__ ushort f2b(float f) {
  union { float f; unsigned u; } x; x.f = f;
  unsigned r = x.u + 0x7fffu + ((x.u >> 16) & 1u);
  return (ushort)(r >> 16);
}

__device__ __forceinline__ void load_lds16(const void* g, void* s) {
  __builtin_amdgcn_global_load_lds((const __attribute__((address_space(1))) void*)g,
                                   (__attribute__((address_space(3))) void*)s,
                                   16, 0, 0);
}

#define WAITV4() asm volatile("s_waitcnt vmcnt(4)" ::: "memory")
#define WAITV0() asm volatile("s_waitcnt vmcnt(0)" ::: "memory")
// lgkm wait needs sched_barrier: hipcc hoists register-only MFMA past inline-asm waits (rule 18)
#define WAITL0() do { asm volatile("s_waitcnt lgkmcnt(0)" ::: "memory"); __builtin_amdgcn_sched_barrier(0); } while (0)
#define BAR()    __builtin_amdgcn_s_barrier()

// ============ 256x256 GEMM — m201-style 8-phase C-quadrant schedule (bf16 NT) ============
// 512 thr = 8 waves (2M x 4N), per-wave C = 128x64. LDS: 2 buffers x {A-h0,A-h1,B-h0,B-h1}
// half-tile regions of [128 rows][64 k] bf16 (16 KB each) = 128 KiB. Tile = K=64.
// 8 phases / 2 K-tiles; phase = {ds_read quadrant frags (0/4/8/12, reg-reuse across phases);
//   stage 1 half-tile (2 x global_load_lds); BAR; lgkm0; setprio1; 16 MFMA; setprio0; BAR}.
// Stage order per iter: A1h0,A1h1,B0h0(t+2),B0h1,A0h0(t+2),A0h1,B1h0(t+3),B1h1; vmcnt(4)
// at ph4/ph8 retires exactly the half-tiles read next (FIFO ledger verified).
// Swizzle: LDS[r][cl] = src[r][cl^(r&7)] (16B chunks); read chunk = (ks*4+khl)^(fr&7)
// -> 2-way max bank aliasing (free). Staged via pre-swizzled per-lane global source.
// EPI: 1 bf16 acc+bias | 2 bf16 gelu(acc+bias) | 3 bf16 acc | 4 bf16 Cold+acc+bias+add
template <int EPI>
__global__ __launch_bounds__(512, 1) void gemm256(
    const ushort* __restrict__ A, const ushort* __restrict__ Bt,
    ushort* __restrict__ C, const float* __restrict__ bias,
    const ushort* __restrict__ addm,
    int K, int lda, int ldb, int ldc)
{
  __shared__ ushort lds[65536];
  const int t = threadIdx.x, w = t >> 6, lane = t & 63;
  const int fr = lane & 15, khl = lane >> 4;
  const int wr = w >> 2, wc = w & 3;

  // bijective XCD swizzle (nwg % 8 == 0 at all call sites)
  const int gx = gridDim.x;
  const int id = blockIdx.y * gx + blockIdx.x;
  const int nwg = gx * gridDim.y;
  const int swz = (id & 7) * (nwg >> 3) + (id >> 3);
  const int m0 = (swz % gx) * 256, n0 = (swz / gx) * 256;

  // fragment read bases (ushort units within a buffer)
  const int cs0 = (khl ^ (fr & 7)) * 8;          // ks=0 chunk
  const int cs1 = ((4 + khl) ^ (fr & 7)) * 8;    // ks=1 chunk
  const int rowA = wr * 8192 + fr * 64;                                  // A-h(wr)
  const int rowB = 16384 + (wc >> 1) * 8192 + ((wc & 1) * 64 + fr) * 64; // B-h(wc>>1)

  // stage source/dst per-thread (pre-swizzled source chunk; LDS write linear)
  const int srow = w * 8 + (lane >> 3);
  const int scol = ((lane & 7) ^ ((lane >> 3) & 7)) * 8;
  const int sR   = w * 512;

  f32x4 acc[8][4] = {};
  bf16x8 a[4][2], b[4][2];

  // region bases (ushort): buf0: A-h0=0, A-h1=8192, B-h0=16384, B-h1=24576; buf1 = +32768
#define STG(P, grow, ld, kt, RG) do { \
    const ushort* s0_ = (P) + (size_t)((grow) + srow) * (ld) + (kt) + scol; \
    load_lds16(s0_, &lds[(RG) + sR]); \
    load_lds16(s0_ + (size_t)64 * (ld), &lds[(RG) + 4096 + sR]); } while (0)
#define LDA4(buf, mh) do { _Pragma("unroll") for (int m_ = 0; m_ < 4; ++m_) { \
    a[m_][0] = *(const bf16x8*)&lds[(buf) + rowA + ((mh) * 4 + m_) * 1024 + cs0]; \
    a[m_][1] = *(const bf16x8*)&lds[(buf) + rowA + ((mh) * 4 + m_) * 1024 + cs1]; } } while (0)
#define LDB2(buf, nh) do { _Pragma("unroll") for (int n_ = 0; n_ < 2; ++n_) { \
    b[(nh) * 2 + n_][0] = *(const bf16x8*)&lds[(buf) + rowB + ((nh) * 2 + n_) * 1024 + cs0]; \
    b[(nh) * 2 + n_][1] = *(const bf16x8*)&lds[(buf) + rowB + ((nh) * 2 + n_) * 1024 + cs1]; } } while (0)
#define Q16(mh, nh) do { __builtin_amdgcn_s_setprio(1); \
    _Pragma("unroll") for (int ks_ = 0; ks_ < 2; ++ks_) \
    _Pragma("unroll") for (int m_ = 0; m_ < 4; ++m_) \
    _Pragma("unroll") for (int n_ = 0; n_ < 2; ++n_) \
      acc[(mh) * 4 + m_][(nh) * 2 + n_] = __builtin_amdgcn_mfma_f32_16x16x32_bf16( \
          a[m_][ks_], b[(nh) * 2 + n_][ks_], acc[(mh) * 4 + m_][(nh) * 2 + n_], 0, 0, 0); \
    __builtin_amdgcn_s_setprio(0); } while (0)

  // prologue: tile0 (B0,A0) + tile1's B halves; vmcnt(4) lands tile0, leaves B1 in flight
  STG(Bt, n0,       ldb, 0,  16384);
  STG(Bt, n0 + 128, ldb, 0,  24576);
  STG(A,  m0,       lda, 0,  0);
  STG(A,  m0 + 128, lda, 0,  8192);
  STG(Bt, n0,       ldb, 64, 32768 + 16384);
  STG(Bt, n0 + 128, ldb, 64, 32768 + 24576);
  WAITV4(); BAR();

  const int NI = K >> 7;   // iterations of 2 K-tiles; NI >= 2, K % 128 == 0
  int kA = 0;
#pragma unroll 1
  for (int i = 0; i < NI - 1; ++i, kA += 128) {
    // ph1: q(0,0) of tile t (buf0); stage A1-h0 (tile t+1)
    LDA4(0, 0); LDB2(0, 0);
    STG(A, m0, lda, kA + 64, 32768);
    BAR(); WAITL0(); Q16(0, 0); BAR();
    // ph2: q(0,1); stage A1-h1
    LDB2(0, 1);
    STG(A, m0 + 128, lda, kA + 64, 32768 + 8192);
    BAR(); WAITL0(); Q16(0, 1); BAR();
    // ph3: q(1,1); stage B0-h0 (tile t+2)
    LDA4(0, 1);
    STG(Bt, n0, ldb, kA + 128, 16384);
    BAR(); WAITL0(); Q16(1, 1); BAR();
    // ph4: q(1,0); stage B0-h1; vmcnt(4) lands {B1(prev), A1} for ph5
    STG(Bt, n0 + 128, ldb, kA + 128, 24576);
    BAR(); Q16(1, 0); WAITV4(); BAR();
    // ph5: q(0,0) of tile t+1 (buf1); stage A0-h0 (tile t+2)
    LDA4(32768, 0); LDB2(32768, 0);
    STG(A, m0, lda, kA + 128, 0);
    BAR(); WAITL0(); Q16(0, 0); BAR();
    // ph6: q(0,1); stage A0-h1
    LDB2(32768, 1);
    STG(A, m0 + 128, lda, kA + 128, 8192);
    BAR(); WAITL0(); Q16(0, 1); BAR();
    // ph7: q(1,1); stage B1-h0 (tile t+3)
    LDA4(32768, 1);
    STG(Bt, n0, ldb, kA + 192, 32768 + 16384);
    BAR(); WAITL0(); Q16(1, 1); BAR();
    // ph8: q(1,0); stage B1-h1; vmcnt(4) lands {B0, A0} for next iter ph1
    STG(Bt, n0 + 128, ldb, kA + 192, 32768 + 24576);
    BAR(); Q16(1, 0); WAITV4(); BAR();
  }
  { // final iteration (kA = K-128): only A1 halves left to stage
    LDA4(0, 0); LDB2(0, 0);
    STG(A, m0, lda, kA + 64, 32768);
    BAR(); WAITL0(); Q16(0, 0); BAR();
    LDB2(0, 1);
    STG(A, m0 + 128, lda, kA + 64, 32768 + 8192);
    BAR(); WAITL0(); Q16(0, 1); BAR();
    LDA4(0, 1);
    BAR(); WAITL0(); Q16(1, 1); BAR();
    Q16(1, 0); WAITV0(); BAR();
    // tile t+1 (buf1): fully landed, no more LDS writes -> no barriers needed
    LDA4(32768, 0); LDB2(32768, 0);
    WAITL0(); Q16(0, 0);
    LDB2(32768, 1);
    WAITL0(); Q16(0, 1);
    LDA4(32768, 1);
    WAITL0(); Q16(1, 1);
    Q16(1, 0);
  }
#undef STG
#undef LDA4
#undef LDB2
#undef Q16

  // epilogue: C/D col=lane&15, row=(lane>>4)*4+reg  [m89-verified]
  const int r0 = khl * 4;
#pragma unroll
  for (int m = 0; m < 8; ++m)
#pragma unroll
    for (int nf = 0; nf < 4; ++nf) {
      const int gr = m0 + wr * 128 + m * 16 + r0;
      const int gc = n0 + wc * 64 + nf * 16 + fr;
      const float bb = (EPI == 3) ? 0.f : bias[gc];
#pragma unroll
      for (int r = 0; r < 4; ++r) {
        const size_t idx = (size_t)(gr + r) * ldc + gc;
        float v = acc[m][nf][r];
        if constexpr (EPI == 1) v += bb;
        if constexpr (EPI == 2) { v += bb; v = 0.5f * v * (1.f + erff(v * 0.7071067811865475f)); }
        if constexpr (EPI == 4) v += bb + b2f(addm[idx]) + b2f(C[idx]);
        C[idx] = f2b(v);
      }
    }
}

// ================= legacy 128x128 GEMM (scores / PV) =================
// z-decode: zb=z&15, zh=z>>4; A += zb*sA+zh*sA2; Bt += zb*sB+zh*sB2; C += z*sC
// EPI 0: f32 store acc*alpha   EPI 3: bf16 store acc*alpha
template <int EPI>
__global__ __launch_bounds__(256, 2) void gemm_nt(
    const ushort* __restrict__ Aall, const ushort* __restrict__ Ball,
    void* __restrict__ Call, int K, int lda, int ldb, int ldc,
    long sA, long sB, long sC, long sA2, long sB2, float alpha)
{
  __shared__ ushort lA[4096];
  __shared__ ushort lB[4096];
  const int t = threadIdx.x;
  const int m0 = blockIdx.x * 128, n0 = blockIdx.y * 128;
  const int zb = blockIdx.z & 15, zh = blockIdx.z >> 4;
  const ushort* A  = Aall + (size_t)zb * sA + (size_t)zh * sA2;
  const ushort* Bt = Ball + (size_t)zb * sB + (size_t)zh * sB2;
  const int lane = t & 63;
  const int wave = t >> 6;
  const int wm = (wave >> 1) * 64, wn = (wave & 1) * 64;
  const int fr = lane & 15, kh = lane >> 4;
  f32x4 acc[4][4] = {};
  const int srow = t >> 2;
  const int scol = (t & 3) * 8;
  const size_t ar0 = (size_t)(m0 + srow) * lda + scol;
  const size_t ar1 = (size_t)(m0 + 64 + srow) * lda + scol;
  const size_t br0 = (size_t)(n0 + srow) * ldb + scol;
  const size_t br1 = (size_t)(n0 + 64 + srow) * ldb + scol;
  const int wbase = wave * 512;

  for (int k0 = 0; k0 < K; k0 += 32) {
    __syncthreads();
    load_lds16(A + ar0 + k0,  &lA[wbase]);
    load_lds16(A + ar1 + k0,  &lA[2048 + wbase]);
    load_lds16(Bt + br0 + k0, &lB[wbase]);
    load_lds16(Bt + br1 + k0, &lB[2048 + wbase]);
    __syncthreads();
    bf16x8 af[4], bg[4];
#pragma unroll
    for (int i = 0; i < 4; ++i)
      af[i] = *(const bf16x8*)&lA[(wm + i * 16 + fr) * 32 + kh * 8];
#pragma unroll
    for (int j = 0; j < 4; ++j)
      bg[j] = *(const bf16x8*)&lB[(wn + j * 16 + fr) * 32 + kh * 8];
#pragma unroll
    for (int i = 0; i < 4; ++i)
#pragma unroll
      for (int j = 0; j < 4; ++j)
        acc[i][j] = __builtin_amdgcn_mfma_f32_16x16x32_bf16(af[i], bg[j], acc[i][j], 0, 0, 0);
  }

  const int r0 = kh * 4;
  if constexpr (EPI == 0) {
    float* C = (float*)Call + (size_t)blockIdx.z * sC;
#pragma unroll
    for (int i = 0; i < 4; ++i)
#pragma unroll
      for (int j = 0; j < 4; ++j) {
        const int gr = m0 + wm + i * 16 + r0;
        const int gc = n0 + wn + j * 16 + fr;
#pragma unroll
        for (int r = 0; r < 4; ++r)
          C[(size_t)(gr + r) * ldc + gc] = acc[i][j][r] * alpha;
      }
  } else {
    ushort* C = (ushort*)Call + (size_t)blockIdx.z * sC;
#pragma unroll
    for (int i = 0; i < 4; ++i)
#pragma unroll
      for (int j = 0; j < 4; ++j) {
        const int gr = m0 + wm + i * 16 + r0;
        const int gc = n0 + wn + j * 16 + fr;
#pragma unroll
        for (int r = 0; r < 4; ++r)
          C[(size_t)(gr + r) * ldc + gc] = f2b(acc[i][j][r] * alpha);
      }
  }
}

// ---------------- reductions ----------------
__device__ __forceinline__ float block_sum(float v, float* red) {
#pragma unroll
  for (int o = 32; o > 0; o >>= 1) v += __shfl_down(v, o, 64);
  __syncthreads();
  if ((threadIdx.x & 63) == 0) red[threadIdx.x >> 6] = v;
  __syncthreads();
  return red[0] + red[1] + red[2] + red[3];
}
__device__ __forceinline__ float block_max(float v, float* red) {
#pragma unroll
  for (int o = 32; o > 0; o >>= 1) v = fmaxf(v, __shfl_down(v, o, 64));
  __syncthreads();
  if ((threadIdx.x & 63) == 0) red[threadIdx.x >> 6] = v;
  __syncthreads();
  return fmaxf(fmaxf(red[0], red[1]), fmaxf(red[2], red[3]));
}

// ---------------- elementwise / transpose kernels ----------------
__global__ __launch_bounds__(256) void k_rms_part(const float* __restrict__ x, float* __restrict__ part) {
  const int c = blockIdx.x * 256 + threadIdx.x;
  const int sl = blockIdx.y;
  const int b = blockIdx.z;
  const float* p = x + (size_t)b * S_ * C_ + c;
  const int s0 = sl * 256;
  float s = 0.f;
  for (int i = 0; i < 256; ++i) { float v = p[(size_t)(s0 + i) * C_]; s += v * v; }
  part[((size_t)b * C_ + c) * 8 + sl] = s;
}
__global__ __launch_bounds__(256) void k_rms_fin(const float* __restrict__ part, float* __restrict__ rms1) {
  const int i = blockIdx.x * 256 + threadIdx.x;
  const float* p = part + (size_t)i * 8;
  float s = 0.f;
#pragma unroll
  for (int j = 0; j < 8; ++j) s += p[j];
  rms1[i] = rsqrtf(s * (1.f / S_) + 1e-8f);
}

__global__ __launch_bounds__(256) void k_trans_norm(const float* __restrict__ x, const float* __restrict__ rms1,
                                                    const float* __restrict__ w,
                                                    ushort* __restrict__ aT, ushort* __restrict__ xT) {
  __shared__ float tile[32][33];
  const int s0 = blockIdx.x * 32, c0 = blockIdx.y * 32, b = blockIdx.z;
  const int tx = threadIdx.x, ty = threadIdx.y;
  const float* xb = x + (size_t)b * S_ * C_;
#pragma unroll
  for (int r = 0; r < 4; ++r) {
    const int s = ty + 8 * r;
    tile[s][tx] = xb[(size_t)(s0 + s) * C_ + c0 + tx];
  }
  __syncthreads();
#pragma unroll
  for (int r = 0; r < 4; ++r) {
    const int c = ty + 8 * r;
    const float v = tile[tx][c];
    const float rm = rms1[b * C_ + c0 + c];
    const size_t o = ((size_t)b * C_ + c0 + c) * S_ + s0 + tx;
    xT[o] = f2b(v);
    aT[o] = f2b(v * rm * w[s0 + tx]);
  }
}

__global__ __launch_bounds__(256) void k_wtrans(const float* __restrict__ W, ushort* __restrict__ WT,
                                                int Kd, int Ndstride, int n_base) {
  __shared__ float tile[32][33];
  const int k0 = blockIdx.x * 32, n0 = blockIdx.y * 32;
  const int tx = threadIdx.x, ty = threadIdx.y;
#pragma unroll
  for (int r = 0; r < 4; ++r) {
    const int k = ty + 8 * r;
    tile[k][tx] = W[(size_t)(k0 + k) * Ndstride + n_base + n0 + tx];
  }
  __syncthreads();
#pragma unroll
  for (int r = 0; r < 4; ++r) {
    const int n = ty + 8 * r;
    WT[(size_t)(n0 + n) * Kd + k0 + tx] = f2b(tile[tx][n]);
  }
}

__global__ __launch_bounds__(256) void k_bt(const ushort* __restrict__ in, ushort* __restrict__ out, int R, int CL) {
  __shared__ ushort tile[32][33];
  const int r0 = blockIdx.x * 32, c0 = blockIdx.y * 32;
  const size_t zb = (size_t)blockIdx.z * R * CL;
  const int tx = threadIdx.x, ty = threadIdx.y;
#pragma unroll
  for (int r = 0; r < 4; ++r) {
    const int rr = ty + 8 * r;
    tile[rr][tx] = in[zb + (size_t)(r0 + rr) * CL + c0 + tx];
  }
  __syncthreads();
#pragma unroll
  for (int r = 0; r < 4; ++r) {
    const int cc = ty + 8 * r;
    out[zb + (size_t)(c0 + cc) * R + r0 + tx] = tile[tx][cc];
  }
}

__device__ __forceinline__ float trend5(const ushort* p, int s) {
  float sum = 0.f;
#pragma unroll
  for (int d = -2; d <= 2; ++d) {
    int ss = s + d; ss = ss < 0 ? 0 : (ss > S_ - 1 ? S_ - 1 : ss);
    sum += b2f(p[ss]);
  }
  return sum * 0.2f;
}
__global__ __launch_bounds__(256) void k_dtrend(const ushort* __restrict__ aT, ushort* __restrict__ trT) {
  const size_t i = (size_t)blockIdx.x * 256 + threadIdx.x;
  const int s = (int)(i & (S_ - 1));
  trT[i] = f2b(trend5(aT + (i - s), s));
}
__global__ __launch_bounds__(256) void k_dseason(const ushort* __restrict__ aT, ushort* __restrict__ seT) {
  const size_t i = (size_t)blockIdx.x * 256 + threadIdx.x;
  const int s = (int)(i & (S_ - 1));
  const ushort* p = aT + (i - s);
  seT[i] = f2b(b2f(p[s]) - trend5(p, s));
}

__global__ __launch_bounds__(256) void k_lambda(const float* __restrict__ lq1, const float* __restrict__ lk1,
                                                const float* __restrict__ lq2, const float* __restrict__ lk2,
                                                float* __restrict__ lam) {
  __shared__ float r1[4], r2[4];
  const int t = threadIdx.x;
  float s1 = 0.f, s2 = 0.f;
  for (int i = t; i < S_; i += 256) { s1 += lq1[i] * lk1[i]; s2 += lq2[i] * lk2[i]; }
#pragma unroll
  for (int o = 32; o > 0; o >>= 1) { s1 += __shfl_down(s1, o, 64); s2 += __shfl_down(s2, o, 64); }
  if ((t & 63) == 0) { r1[t >> 6] = s1; r2[t >> 6] = s2; }
  __syncthreads();
  if (t == 0) {
    const float a = r1[0] + r1[1] + r1[2] + r1[3];
    const float b = r2[0] + r2[1] + r2[2] + r2[3];
    *lam = expf(a) - expf(b) + LAMBDA_INIT_F;
  }
}

__global__ __launch_bounds__(256) void k_softmax(const float* __restrict__ a1, const float* __restrict__ a2,
                                                 const float* __restrict__ lamp, ushort* __restrict__ dm) {
  __shared__ float red[4];
  const size_t row = blockIdx.x;
  const float* p1 = a1 + row * 512;
  const float* p2 = a2 + row * 512;
  const int t = threadIdx.x;
  const float v1a = p1[t], v1b = p1[t + 256];
  const float v2a = p2[t], v2b = p2[t + 256];
  const float m1 = block_max(fmaxf(v1a, v1b), red);
  const float m2 = block_max(fmaxf(v2a, v2b), red);
  const float e1a = expf(v1a - m1), e1b = expf(v1b - m1);
  const float e2a = expf(v2a - m2), e2b = expf(v2b - m2);
  const float s1 = block_sum(e1a + e1b, red);
  const float s2 = block_sum(e2a + e2b, red);
  const float i1 = 1.f / s1, i2 = (*lamp) / s2;
  ushort* o = dm + row * 512;
  o[t]       = f2b(e1a * i1 - e2a * i2);
  o[t + 256] = f2b(e1b * i1 - e2b * i2);
}

__global__ __launch_bounds__(256) void k_postattn(const ushort* __restrict__ P, const ushort* __restrict__ xT,
                                                  const float* __restrict__ norm_w, const float* __restrict__ ln_ff_w,
                                                  ushort* __restrict__ attn, ushort* __restrict__ h) {
  __shared__ float red[4];
  const size_t row = blockIdx.x;
  const ushort* p = P + row * S_;
  const int t = threadIdx.x;
  float v[8]; float ss = 0.f;
#pragma unroll
  for (int i = 0; i < 8; ++i) { v[i] = b2f(p[t + 256 * i]); ss += v[i] * v[i]; }
  ss = block_sum(ss, red);
  const float inv = rsqrtf(ss * (1.f / S_) + 1e-8f);
  const ushort* xr = xT + row * S_;
  ushort* ar = attn + row * S_;
  float x2[8]; float ss2 = 0.f;
#pragma unroll
  for (int i = 0; i < 8; ++i) {
    const int s = t + 256 * i;
    const float at = v[i] * inv * norm_w[s] * ONE_M_LI_F;
    ar[s] = f2b(at);
    const float xx = b2f(xr[s]) + at;
    x2[i] = xx; ss2 += xx * xx;
  }
  ss2 = block_sum(ss2, red);
  const float inv2 = rsqrtf(ss2 * (1.f / S_) + 1e-8f);
  ushort* hr = h + row * S_;
#pragma unroll
  for (int i = 0; i < 8; ++i) { const int s = t + 256 * i; hr[s] = f2b(x2[i] * inv2 * ln_ff_w[s]); }
}

// out[b,s,c] = x[b,s,c] + sumT[b,c,s]   (sumT = attn+ffo, folded in FFN2b epilogue)
__global__ __launch_bounds__(256) void k_final2(const float* __restrict__ x, const ushort* __restrict__ sumT,
                                                float* __restrict__ out) {
  __shared__ float tile[32][33];
  const int s0 = blockIdx.x * 32, c0 = blockIdx.y * 32, b = blockIdx.z;
  const int tx = threadIdx.x, ty = threadIdx.y;
#pragma unroll
  for (int r = 0; r < 4; ++r) {
    const int c = ty + 8 * r;
    tile[c][tx] = b2f(sumT[((size_t)b * C_ + c0 + c) * S_ + s0 + tx]);
  }
  __syncthreads();
#pragma unroll
  for (int r = 0; r < 4; ++r) {
    const int s = ty + 8 * r;
    const size_t o = ((size_t)b * S_ + s0 + s) * C_ + c0 + tx;
    out[o] = x[o] + tile[tx][s];
  }
}

__global__ void k_probe(float* out, float v) { out[0] = v; }

// ---------------- launch ----------------
extern "C" void kernel_launch(void* const* d_in, const int* in_sizes, int n_in,
                              void* d_out, int out_size, void* d_ws, size_t ws_size,
                              hipStream_t stream) {
  const float* x       = (const float*)d_in[0];
  const float* ln_attn = (const float*)d_in[1];
  const float* q12_w   = (const float*)d_in[2];
  const float* q12_b   = (const float*)d_in[3];
  const float* k12_w   = (const float*)d_in[4];
  const float* k12_b   = (const float*)d_in[5];
  const float* v_w     = (const float*)d_in[6];
  const float* v_b     = (const float*)d_in[7];
  const float* lq1     = (const float*)d_in[8];
  const float* lk1     = (const float*)d_in[9];
  const float* lq2     = (const float*)d_in[10];
  const float* lk2     = (const float*)d_in[11];
  const float* norm_w  = (const float*)d_in[12];
  const float* ln_ff   = (const float*)d_in[13];
  const float* ff_w1   = (const float*)d_in[14];
  const float* ff_b1   = (const float*)d_in[15];
  const float* ff_w2   = (const float*)d_in[16];
  const float* ff_b2   = (const float*)d_in[17];
  float* out = (float*)d_out;

  if (ws_size < 184844544ull) {
    k_probe<<<1, 1, 0, stream>>>(out, (float)(ws_size >> 20));
    return;
  }

  char* ws = (char*)d_ws;
  ushort* slotA = (ushort*)(ws + 0);
  ushort* slotB = (ushort*)(ws + 33554432);
  ushort* slotC = (ushort*)(ws + 67108864);
  ushort* slotD = (ushort*)(ws + 100663296);
  ushort* slotE = (ushort*)(ws + 134217728);
  ushort* slotF = (ushort*)(ws + 167772160);
  float*  part  = (float*) (ws + 184549376);
  float*  rms1  = (float*) (ws + 184811520);
  float*  lamp  = (float*) (ws + 184844288);

  ushort* aT   = slotA;               // trans_norm .. dseason
  ushort* xT   = slotE;               // trans_norm .. postattn
  ushort* Vm   = slotB;               // V gemm .. k_bt
  ushort* VT   = slotD;               // k_bt .. PV
  ushort* trT  = slotB;               // dtrend .. Q-proj
  ushort* seT  = slotC;               // dseason .. K-proj
  ushort* K12  = slotA;               // [8192,4096] spans A+B
  float*  scr  = (float*)slotC;       // scores [2][16][512][512] f32
  ushort* Pm   = slotB;               // PV out [B,C,S]
  ushort* attn = slotC;               // postattn .. FFN2b
  ushort* hbuf = slotA;               // postattn .. FFN1b
  ushort* ff1T = slotB;               // [8192,2048]
  ushort* ff2T = slotD;               // [2048,8192]
  ushort* ffo  = slotE;               // final attn+ffo (xT dead)
  ushort* wsl  = slotF;               // vwT/q12T/k12T/dmat
  ushort* dmat = slotF;
  ushort* Qm   = (ushort*)d_out;      // [8192,4096] bf16 (dead after scores)
  ushort* H1   = (ushort*)d_out;      // [8192,4096] bf16 per FFN half

  const dim3 blk256(256), blk512(512), blkT(32, 8);

  // seq-axis rmsnorm + transpose
  k_rms_part<<<dim3(2, 8, B_), blk256, 0, stream>>>(x, part);
  k_rms_fin<<<dim3(32), blk256, 0, stream>>>(part, rms1);
  k_trans_norm<<<dim3(64, 16, B_), blkT, 0, stream>>>(x, rms1, ln_attn, aT, xT);

  // V path
  k_wtrans<<<dim3(64, 64), blkT, 0, stream>>>(v_w, wsl, 2048, 2048, 0);
  gemm256<1><<<dim3(32, 8), blk512, 0, stream>>>(aT, wsl, Vm, v_b, nullptr, 2048, 2048, 2048, 2048);
  k_bt<<<dim3(16, 64, B_), blkT, 0, stream>>>(Vm, VT, 512, 2048);

  // trend -> Q (d_out)
  k_dtrend<<<dim3(65536), blk256, 0, stream>>>(aT, trT);
  k_wtrans<<<dim3(64, 128), blkT, 0, stream>>>(q12_w, wsl, 2048, 4096, 0);
  gemm256<1><<<dim3(32, 16), blk512, 0, stream>>>(trT, wsl, Qm, q12_b, nullptr, 2048, 2048, 2048, 4096);

  // seasonal -> K12 (A+B)
  k_dseason<<<dim3(65536), blk256, 0, stream>>>(aT, seT);
  k_lambda<<<dim3(1), blk256, 0, stream>>>(lq1, lk1, lq2, lk2, lamp);
  k_wtrans<<<dim3(64, 128), blkT, 0, stream>>>(k12_w, wsl, 2048, 4096, 0);
  gemm256<1><<<dim3(32, 16), blk512, 0, stream>>>(seT, wsl, K12, k12_b, nullptr, 2048, 2048, 2048, 4096);

  // scores (legacy 128^2, z = half*16 + b) -> scr[half][b][512][512]
  gemm_nt<0><<<dim3(4, 4, 32), blk256, 0, stream>>>(Qm, K12, scr, 2048, 4096, 4096, 512,
                                                    512L * 4096, 512L * 4096, 512L * 512,
                                                    2048L, 2048L, SCALE_F);

  // softmax -> dmat, PV -> Pm
  k_softmax<<<dim3(8192), blk256, 0, stream>>>(scr, scr + 4194304, lamp, dmat);
  gemm_nt<3><<<dim3(4, 16, B_), blk256, 0, stream>>>(dmat, VT, Pm, 512, 512, 512, 2048,
                                                     512L * 512, 2048L * 512, 512L * 2048,
                                                     0, 0, 1.f);

  // post-attn fused norms: attn->C, hbuf->A
  k_postattn<<<dim3(8192), blk256, 0, stream>>>(Pm, xT, norm_w, ln_ff, attn, hbuf);

  // FFN weights: ff1T->B, ff2T->D
  k_wtrans<<<dim3(64, 256), blkT, 0, stream>>>(ff_w1, ff1T, 2048, 8192, 0);
  k_wtrans<<<dim3(256, 64), blkT, 0, stream>>>(ff_w2, ff2T, 8192, 2048, 0);

  // FFN in 2 N-halves of H, full M=8192 each:
  //   H1 = gelu(hbuf @ ff1T_half + b1)             [8192 x 4096] -> d_out
  //   ffo = H1 @ ff2T_khalf (+ b2 + attn on 2nd)   [8192 x 2048]
  gemm256<2><<<dim3(32, 16), blk512, 0, stream>>>(hbuf, ff1T, H1, ff_b1, nullptr,
                                                  2048, 2048, 2048, 4096);
  gemm256<3><<<dim3(32, 8), blk512, 0, stream>>>(H1, ff2T, ffo, nullptr, nullptr,
                                                 4096, 4096, 8192, 2048);
  gemm256<2><<<dim3(32, 16), blk512, 0, stream>>>(hbuf, ff1T + (size_t)4096 * 2048, H1,
                                                  ff_b1 + 4096, nullptr, 2048, 2048, 2048, 4096);
  gemm256<4><<<dim3(32, 8), blk512, 0, stream>>>(H1, ff2T + 4096, ffo, ff_b2, attn,
                                                 4096, 4096, 8192, 2048);

  // out = x + (attn + ffo)^T
  k_final2<<<dim3(64, 16, B_), blkT, 0, stream>>>(x, ffo, out);
}

// Round 10
// 1227.053 us; speedup vs baseline: 1.1420x; 1.1420x over previous
//
#include <hip/hip_runtime.h>
#include <hip/hip_bf16.h>

#define B_ 16
#define S_ 2048
#define C_ 512
#define H_ 8192

#define LAMBDA_INIT_F 0.3555090675909693f
#define ONE_M_LI_F    0.6444909324090307f
#define SCALE_F       0.14865088937534013f

using bf16x8 = __attribute__((ext_vector_type(8))) short;
using f32x4  = __attribute__((ext_vector_type(4))) float;

__device__ __forceinline__ float b2f(ushort u) {
  union { unsigned u; float f; } x; x.u = ((unsigned)u) << 16; return x.f;
}
__device__ __forceinline__ ushort f2b(float f) {
  union { float f; unsigned u; } x; x.f = f;
  unsigned r = x.u + 0x7fffu + ((x.u >> 16) & 1u);
  return (ushort)(r >> 16);
}

__device__ __forceinline__ void load_lds16(const void* g, void* s) {
  __builtin_amdgcn_global_load_lds((const __attribute__((address_space(1))) void*)g,
                                   (__attribute__((address_space(3))) void*)s,
                                   16, 0, 0);
}

#define WAITV8() asm volatile("s_waitcnt vmcnt(8)" ::: "memory")
#define WAITV4() asm volatile("s_waitcnt vmcnt(4)" ::: "memory")
#define WAITV0() asm volatile("s_waitcnt vmcnt(0)" ::: "memory")
// lgkm wait needs sched_barrier: hipcc hoists register-only MFMA past inline-asm waits (rule 18)
#define WAITL0() do { asm volatile("s_waitcnt lgkmcnt(0)" ::: "memory"); __builtin_amdgcn_sched_barrier(0); } while (0)
#define BAR()    __builtin_amdgcn_s_barrier()

// ================= 256x256 GEMM, fat-phase ring + 2D XCD chunking (bf16 NT) =============
// R6-verified schedule (best measured): ring of 4 k-32 units, 1 barrier/phase,
// phase = {12 ds_read(u); STAGE(u+3); lgkm0; 32 MFMA; vmcnt(8); BAR}.
// NEW: block->(m0,n0) via 2D per-XCD chunks. xcd = id&7 (HW round-robin), l = id>>3.
// Per-XCD sub-grid 8m x (gy/2)n, n-fastest order: the 32 concurrent blocks/XCD touch
// 4m x 8n (or 8m x 4n) panels -> per-K-step unique staging 192KB << 4MB L2.
// Intra-unit layout = R5-verified zero-conflict pair-row swizzle.
// EPI: 1 bf16 acc+bias | 2 bf16 gelu(acc+bias) | 3 bf16 acc | 4 bf16 Cold+acc+bias+add
template <int EPI>
__global__ __launch_bounds__(512, 1) void gemm256(
    const ushort* __restrict__ A, const ushort* __restrict__ Bt,
    ushort* __restrict__ C, const float* __restrict__ bias,
    const ushort* __restrict__ addm,
    int K, int lda, int ldb, int ldc)
{
  __shared__ ushort lds[65536];  // 4 slots x (A 8192 + B 8192) ushorts
  const int t = threadIdx.x, w = t >> 6, lane = t & 63;
  const int fr = lane & 15, khl = lane >> 4;
  const int wr = w >> 2, wc = w & 3;

  // 2D XCD chunking: gx == 32 at all call sites; gy in {8, 16}
  const int gx = gridDim.x, gy = gridDim.y;
  const int id = blockIdx.y * gx + blockIdx.x;
  const int xcd = id & 7, l = id >> 3;
  const int tnb = (gy == 16) ? 3 : 2;          // log2(tn), tn = gy/2
  const int lm = l >> tnb, ln = l & ((1 << tnb) - 1);
  const int m0 = ((xcd & 3) * 8 + lm) * 256;
  const int n0 = ((xcd >> 2) * (1 << tnb) + ln) * 256;

  // staging source (pre-swizzled so linear LDS write == swizzled layout; R5-verified pair)
  const int sl    = (t & 7) ^ ((t >> 3) & 7);
  const int rbase = ((t >> 3) << 1) + (sl >> 2);
  const int khs   = sl & 3;
  const size_t aoff = (size_t)(m0 + rbase) * lda + khs * 8;
  const size_t boff = (size_t)(n0 + rbase) * ldb + khs * 8;
  const size_t jstA = (size_t)128 * lda, jstB = (size_t)128 * ldb;

  // ds_read offsets within a unit (ushort units)
  int ao[8], bo[4];
#pragma unroll
  for (int m = 0; m < 8; ++m) {
    const int row = wr * 128 + m * 16 + fr, dr = row >> 1;
    const int so = (((row & 1) << 2) + khl) ^ (dr & 7);
    ao[m] = dr * 64 + so * 8;
  }
#pragma unroll
  for (int n = 0; n < 4; ++n) {
    const int row = wc * 64 + n * 16 + fr, dr = row >> 1;
    const int so = (((row & 1) << 2) + khl) ^ (dr & 7);
    bo[n] = 8192 + dr * 64 + so * 8;
  }

  f32x4 acc[8][4] = {};
  const int U = K >> 5;   // k-32 units; requires U >= 4

#define STAGE_U(u) do { \
    const ushort* sa_ = A  + aoff + (size_t)(u) * 32; \
    const ushort* sb_ = Bt + boff + (size_t)(u) * 32; \
    ushort* da_ = &lds[((u) & 3) * 16384 + w * 512]; \
    load_lds16(sa_, da_); load_lds16(sa_ + jstA, da_ + 4096); \
    load_lds16(sb_, da_ + 8192); load_lds16(sb_ + jstB, da_ + 12288); } while (0)
#define LDFRAG(u) do { const int sb_ = ((u) & 3) * 16384; \
    _Pragma("unroll") for (int m_ = 0; m_ < 8; ++m_) af[m_] = *(const bf16x8*)&lds[sb_ + ao[m_]]; \
    _Pragma("unroll") for (int n_ = 0; n_ < 4; ++n_) bg[n_] = *(const bf16x8*)&lds[sb_ + bo[n_]]; } while (0)
#define MFMA32() do { __builtin_amdgcn_s_setprio(1); \
    _Pragma("unroll") for (int m_ = 0; m_ < 8; ++m_) \
    _Pragma("unroll") for (int n_ = 0; n_ < 4; ++n_) \
      acc[m_][n_] = __builtin_amdgcn_mfma_f32_16x16x32_bf16(af[m_], bg[n_], acc[m_][n_], 0, 0, 0); \
    __builtin_amdgcn_s_setprio(0); } while (0)

  // prologue: stage units 0,1,2 (12 loads); retire unit 0 (vmcnt 12 -> 8)
  STAGE_U(0); STAGE_U(1); STAGE_U(2);
  WAITV8(); BAR();

  bf16x8 af[8], bg[4];
#pragma unroll 4
  for (int u = 0; u <= U - 4; ++u) {
    LDFRAG(u);
    STAGE_U(u + 3);
    WAITL0();
    MFMA32();
    WAITV8();   // retire unit u+1 (outstanding: u+1,u+2,u+3 = 12 -> 8)
    BAR();
  }
  { // phase U-3: no stage; outstanding {U-2, U-1} = 8 -> retire U-2
    LDFRAG(U - 3);
    WAITL0();
    MFMA32();
    WAITV4();
    BAR();
  }
  { // phase U-2: outstanding {U-1} = 4 -> retire U-1
    LDFRAG(U - 2);
    WAITL0();
    MFMA32();
    WAITV0();
    BAR();
  }
  { // phase U-1: all landed
    LDFRAG(U - 1);
    WAITL0();
    MFMA32();
  }
#undef STAGE_U
#undef LDFRAG
#undef MFMA32

  // epilogue: C/D col=lane&15, row=(lane>>4)*4+reg  [m89-verified]
  const int r0 = khl * 4;
#pragma unroll
  for (int m = 0; m < 8; ++m)
#pragma unroll
    for (int nf = 0; nf < 4; ++nf) {
      const int gr = m0 + wr * 128 + m * 16 + r0;
      const int gc = n0 + wc * 64 + nf * 16 + fr;
      const float bb = (EPI == 3) ? 0.f : bias[gc];
#pragma unroll
      for (int r = 0; r < 4; ++r) {
        const size_t idx = (size_t)(gr + r) * ldc + gc;
        float v = acc[m][nf][r];
        if constexpr (EPI == 1) v += bb;
        if constexpr (EPI == 2) { v += bb; v = 0.5f * v * (1.f + erff(v * 0.7071067811865475f)); }
        if constexpr (EPI == 4) v += bb + b2f(addm[idx]) + b2f(C[idx]);
        C[idx] = f2b(v);
      }
    }
}

// ================= legacy 128x128 GEMM (scores / PV) =================
// z-decode: zb=z&15, zh=z>>4; A += zb*sA+zh*sA2; Bt += zb*sB+zh*sB2; C += z*sC
// EPI 0: f32 store acc*alpha   EPI 3: bf16 store acc*alpha
template <int EPI>
__global__ __launch_bounds__(256, 2) void gemm_nt(
    const ushort* __restrict__ Aall, const ushort* __restrict__ Ball,
    void* __restrict__ Call, int K, int lda, int ldb, int ldc,
    long sA, long sB, long sC, long sA2, long sB2, float alpha)
{
  __shared__ ushort lA[4096];
  __shared__ ushort lB[4096];
  const int t = threadIdx.x;
  const int m0 = blockIdx.x * 128, n0 = blockIdx.y * 128;
  const int zb = blockIdx.z & 15, zh = blockIdx.z >> 4;
  const ushort* A  = Aall + (size_t)zb * sA + (size_t)zh * sA2;
  const ushort* Bt = Ball + (size_t)zb * sB + (size_t)zh * sB2;
  const int lane = t & 63;
  const int wave = t >> 6;
  const int wm = (wave >> 1) * 64, wn = (wave & 1) * 64;
  const int fr = lane & 15, kh = lane >> 4;
  f32x4 acc[4][4] = {};
  const int srow = t >> 2;
  const int scol = (t & 3) * 8;
  const size_t ar0 = (size_t)(m0 + srow) * lda + scol;
  const size_t ar1 = (size_t)(m0 + 64 + srow) * lda + scol;
  const size_t br0 = (size_t)(n0 + srow) * ldb + scol;
  const size_t br1 = (size_t)(n0 + 64 + srow) * ldb + scol;
  const int wbase = wave * 512;

  for (int k0 = 0; k0 < K; k0 += 32) {
    __syncthreads();
    load_lds16(A + ar0 + k0,  &lA[wbase]);
    load_lds16(A + ar1 + k0,  &lA[2048 + wbase]);
    load_lds16(Bt + br0 + k0, &lB[wbase]);
    load_lds16(Bt + br1 + k0, &lB[2048 + wbase]);
    __syncthreads();
    bf16x8 af[4], bg[4];
#pragma unroll
    for (int i = 0; i < 4; ++i)
      af[i] = *(const bf16x8*)&lA[(wm + i * 16 + fr) * 32 + kh * 8];
#pragma unroll
    for (int j = 0; j < 4; ++j)
      bg[j] = *(const bf16x8*)&lB[(wn + j * 16 + fr) * 32 + kh * 8];
#pragma unroll
    for (int i = 0; i < 4; ++i)
#pragma unroll
      for (int j = 0; j < 4; ++j)
        acc[i][j] = __builtin_amdgcn_mfma_f32_16x16x32_bf16(af[i], bg[j], acc[i][j], 0, 0, 0);
  }

  const int r0 = kh * 4;
  if constexpr (EPI == 0) {
    float* C = (float*)Call + (size_t)blockIdx.z * sC;
#pragma unroll
    for (int i = 0; i < 4; ++i)
#pragma unroll
      for (int j = 0; j < 4; ++j) {
        const int gr = m0 + wm + i * 16 + r0;
        const int gc = n0 + wn + j * 16 + fr;
#pragma unroll
        for (int r = 0; r < 4; ++r)
          C[(size_t)(gr + r) * ldc + gc] = acc[i][j][r] * alpha;
      }
  } else {
    ushort* C = (ushort*)Call + (size_t)blockIdx.z * sC;
#pragma unroll
    for (int i = 0; i < 4; ++i)
#pragma unroll
      for (int j = 0; j < 4; ++j) {
        const int gr = m0 + wm + i * 16 + r0;
        const int gc = n0 + wn + j * 16 + fr;
#pragma unroll
        for (int r = 0; r < 4; ++r)
          C[(size_t)(gr + r) * ldc + gc] = f2b(acc[i][j][r] * alpha);
      }
  }
}

// ---------------- reductions ----------------
__device__ __forceinline__ float block_sum(float v, float* red) {
#pragma unroll
  for (int o = 32; o > 0; o >>= 1) v += __shfl_down(v, o, 64);
  __syncthreads();
  if ((threadIdx.x & 63) == 0) red[threadIdx.x >> 6] = v;
  __syncthreads();
  return red[0] + red[1] + red[2] + red[3];
}
__device__ __forceinline__ float block_max(float v, float* red) {
#pragma unroll
  for (int o = 32; o > 0; o >>= 1) v = fmaxf(v, __shfl_down(v, o, 64));
  __syncthreads();
  if ((threadIdx.x & 63) == 0) red[threadIdx.x >> 6] = v;
  __syncthreads();
  return fmaxf(fmaxf(red[0], red[1]), fmaxf(red[2], red[3]));
}

// ---------------- elementwise / transpose kernels ----------------
__global__ __launch_bounds__(256) void k_rms_part(const float* __restrict__ x, float* __restrict__ part) {
  const int c = blockIdx.x * 256 + threadIdx.x;
  const int sl = blockIdx.y;
  const int b = blockIdx.z;
  const float* p = x + (size_t)b * S_ * C_ + c;
  const int s0 = sl * 256;
  float s = 0.f;
  for (int i = 0; i < 256; ++i) { float v = p[(size_t)(s0 + i) * C_]; s += v * v; }
  part[((size_t)b * C_ + c) * 8 + sl] = s;
}
__global__ __launch_bounds__(256) void k_rms_fin(const float* __restrict__ part, float* __restrict__ rms1) {
  const int i = blockIdx.x * 256 + threadIdx.x;
  const float* p = part + (size_t)i * 8;
  float s = 0.f;
#pragma unroll
  for (int j = 0; j < 8; ++j) s += p[j];
  rms1[i] = rsqrtf(s * (1.f / S_) + 1e-8f);
}

__global__ __launch_bounds__(256) void k_trans_norm(const float* __restrict__ x, const float* __restrict__ rms1,
                                                    const float* __restrict__ w,
                                                    ushort* __restrict__ aT, ushort* __restrict__ xT) {
  __shared__ float tile[32][33];
  const int s0 = blockIdx.x * 32, c0 = blockIdx.y * 32, b = blockIdx.z;
  const int tx = threadIdx.x, ty = threadIdx.y;
  const float* xb = x + (size_t)b * S_ * C_;
#pragma unroll
  for (int r = 0; r < 4; ++r) {
    const int s = ty + 8 * r;
    tile[s][tx] = xb[(size_t)(s0 + s) * C_ + c0 + tx];
  }
  __syncthreads();
#pragma unroll
  for (int r = 0; r < 4; ++r) {
    const int c = ty + 8 * r;
    const float v = tile[tx][c];
    const float rm = rms1[b * C_ + c0 + c];
    const size_t o = ((size_t)b * C_ + c0 + c) * S_ + s0 + tx;
    xT[o] = f2b(v);
    aT[o] = f2b(v * rm * w[s0 + tx]);
  }
}

__global__ __launch_bounds__(256) void k_wtrans(const float* __restrict__ W, ushort* __restrict__ WT,
                                                int Kd, int Ndstride, int n_base) {
  __shared__ float tile[32][33];
  const int k0 = blockIdx.x * 32, n0 = blockIdx.y * 32;
  const int tx = threadIdx.x, ty = threadIdx.y;
#pragma unroll
  for (int r = 0; r < 4; ++r) {
    const int k = ty + 8 * r;
    tile[k][tx] = W[(size_t)(k0 + k) * Ndstride + n_base + n0 + tx];
  }
  __syncthreads();
#pragma unroll
  for (int r = 0; r < 4; ++r) {
    const int n = ty + 8 * r;
    WT[(size_t)(n0 + n) * Kd + k0 + tx] = f2b(tile[tx][n]);
  }
}

__global__ __launch_bounds__(256) void k_bt(const ushort* __restrict__ in, ushort* __restrict__ out, int R, int CL) {
  __shared__ ushort tile[32][33];
  const int r0 = blockIdx.x * 32, c0 = blockIdx.y * 32;
  const size_t zb = (size_t)blockIdx.z * R * CL;
  const int tx = threadIdx.x, ty = threadIdx.y;
#pragma unroll
  for (int r = 0; r < 4; ++r) {
    const int rr = ty + 8 * r;
    tile[rr][tx] = in[zb + (size_t)(r0 + rr) * CL + c0 + tx];
  }
  __syncthreads();
#pragma unroll
  for (int r = 0; r < 4; ++r) {
    const int cc = ty + 8 * r;
    out[zb + (size_t)(c0 + cc) * R + r0 + tx] = tile[tx][cc];
  }
}

__device__ __forceinline__ float trend5(const ushort* p, int s) {
  float sum = 0.f;
#pragma unroll
  for (int d = -2; d <= 2; ++d) {
    int ss = s + d; ss = ss < 0 ? 0 : (ss > S_ - 1 ? S_ - 1 : ss);
    sum += b2f(p[ss]);
  }
  return sum * 0.2f;
}
// fused trend+seasonal: one read pass, two writes
__global__ __launch_bounds__(256) void k_decomp2(const ushort* __restrict__ aT,
                                                 ushort* __restrict__ trT, ushort* __restrict__ seT) {
  const size_t i = (size_t)blockIdx.x * 256 + threadIdx.x;
  const int s = (int)(i & (S_ - 1));
  const ushort* p = aT + (i - s);
  const float tr = trend5(p, s);
  trT[i] = f2b(tr);
  seT[i] = f2b(b2f(p[s]) - tr);
}

__global__ __launch_bounds__(256) void k_lambda(const float* __restrict__ lq1, const float* __restrict__ lk1,
                                                const float* __restrict__ lq2, const float* __restrict__ lk2,
                                                float* __restrict__ lam) {
  __shared__ float r1[4], r2[4];
  const int t = threadIdx.x;
  float s1 = 0.f, s2 = 0.f;
  for (int i = t; i < S_; i += 256) { s1 += lq1[i] * lk1[i]; s2 += lq2[i] * lk2[i]; }
#pragma unroll
  for (int o = 32; o > 0; o >>= 1) { s1 += __shfl_down(s1, o, 64); s2 += __shfl_down(s2, o, 64); }
  if ((t & 63) == 0) { r1[t >> 6] = s1; r2[t >> 6] = s2; }
  __syncthreads();
  if (t == 0) {
    const float a = r1[0] + r1[1] + r1[2] + r1[3];
    const float b = r2[0] + r2[1] + r2[2] + r2[3];
    *lam = expf(a) - expf(b) + LAMBDA_INIT_F;
  }
}

__global__ __launch_bounds__(256) void k_softmax(const float* __restrict__ a1, const float* __restrict__ a2,
                                                 const float* __restrict__ lamp, ushort* __restrict__ dm) {
  __shared__ float red[4];
  const size_t row = blockIdx.x;
  const float* p1 = a1 + row * 512;
  const float* p2 = a2 + row * 512;
  const int t = threadIdx.x;
  const float v1a = p1[t], v1b = p1[t + 256];
  const float v2a = p2[t], v2b = p2[t + 256];
  const float m1 = block_max(fmaxf(v1a, v1b), red);
  const float m2 = block_max(fmaxf(v2a, v2b), red);
  const float e1a = expf(v1a - m1), e1b = expf(v1b - m1);
  const float e2a = expf(v2a - m2), e2b = expf(v2b - m2);
  const float s1 = block_sum(e1a + e1b, red);
  const float s2 = block_sum(e2a + e2b, red);
  const float i1 = 1.f / s1, i2 = (*lamp) / s2;
  ushort* o = dm + row * 512;
  o[t]       = f2b(e1a * i1 - e2a * i2);
  o[t + 256] = f2b(e1b * i1 - e2b * i2);
}

__global__ __launch_bounds__(256) void k_postattn(const ushort* __restrict__ P, const ushort* __restrict__ xT,
                                                  const float* __restrict__ norm_w, const float* __restrict__ ln_ff_w,
                                                  ushort* __restrict__ attn, ushort* __restrict__ h) {
  __shared__ float red[4];
  const size_t row = blockIdx.x;
  const ushort* p = P + row * S_;
  const int t = threadIdx.x;
  float v[8]; float ss = 0.f;
#pragma unroll
  for (int i = 0; i < 8; ++i) { v[i] = b2f(p[t + 256 * i]); ss += v[i] * v[i]; }
  ss = block_sum(ss, red);
  const float inv = rsqrtf(ss * (1.f / S_) + 1e-8f);
  const ushort* xr = xT + row * S_;
  ushort* ar = attn + row * S_;
  float x2[8]; float ss2 = 0.f;
#pragma unroll
  for (int i = 0; i < 8; ++i) {
    const int s = t + 256 * i;
    const float at = v[i] * inv * norm_w[s] * ONE_M_LI_F;
    ar[s] = f2b(at);
    const float xx = b2f(xr[s]) + at;
    x2[i] = xx; ss2 += xx * xx;
  }
  ss2 = block_sum(ss2, red);
  const float inv2 = rsqrtf(ss2 * (1.f / S_) + 1e-8f);
  ushort* hr = h + row * S_;
#pragma unroll
  for (int i = 0; i < 8; ++i) { const int s = t + 256 * i; hr[s] = f2b(x2[i] * inv2 * ln_ff_w[s]); }
}

// out[b,s,c] = x[b,s,c] + sumT[b,c,s]   (sumT = attn+ffo, folded in FFN2b epilogue)
__global__ __launch_bounds__(256) void k_final2(const float* __restrict__ x, const ushort* __restrict__ sumT,
                                                float* __restrict__ out) {
  __shared__ float tile[32][33];
  const int s0 = blockIdx.x * 32, c0 = blockIdx.y * 32, b = blockIdx.z;
  const int tx = threadIdx.x, ty = threadIdx.y;
#pragma unroll
  for (int r = 0; r < 4; ++r) {
    const int c = ty + 8 * r;
    tile[c][tx] = b2f(sumT[((size_t)b * C_ + c0 + c) * S_ + s0 + tx]);
  }
  __syncthreads();
#pragma unroll
  for (int r = 0; r < 4; ++r) {
    const int s = ty + 8 * r;
    const size_t o = ((size_t)b * S_ + s0 + s) * C_ + c0 + tx;
    out[o] = x[o] + tile[tx][s];
  }
}

__global__ void k_probe(float* out, float v) { out[0] = v; }

// ---------------- launch ----------------
extern "C" void kernel_launch(void* const* d_in, const int* in_sizes, int n_in,
                              void* d_out, int out_size, void* d_ws, size_t ws_size,
                              hipStream_t stream) {
  const float* x       = (const float*)d_in[0];
  const float* ln_attn = (const float*)d_in[1];
  const float* q12_w   = (const float*)d_in[2];
  const float* q12_b   = (const float*)d_in[3];
  const float* k12_w   = (const float*)d_in[4];
  const float* k12_b   = (const float*)d_in[5];
  const float* v_w     = (const float*)d_in[6];
  const float* v_b     = (const float*)d_in[7];
  const float* lq1     = (const float*)d_in[8];
  const float* lk1     = (const float*)d_in[9];
  const float* lq2     = (const float*)d_in[10];
  const float* lk2     = (const float*)d_in[11];
  const float* norm_w  = (const float*)d_in[12];
  const float* ln_ff   = (const float*)d_in[13];
  const float* ff_w1   = (const float*)d_in[14];
  const float* ff_b1   = (const float*)d_in[15];
  const float* ff_w2   = (const float*)d_in[16];
  const float* ff_b2   = (const float*)d_in[17];
  float* out = (float*)d_out;

  if (ws_size < 184844544ull) {
    k_probe<<<1, 1, 0, stream>>>(out, (float)(ws_size >> 20));
    return;
  }

  char* ws = (char*)d_ws;
  ushort* slotA = (ushort*)(ws + 0);
  ushort* slotB = (ushort*)(ws + 33554432);
  ushort* slotC = (ushort*)(ws + 67108864);
  ushort* slotD = (ushort*)(ws + 100663296);
  ushort* slotE = (ushort*)(ws + 134217728);
  ushort* slotF = (ushort*)(ws + 167772160);
  float*  part  = (float*) (ws + 184549376);
  float*  rms1  = (float*) (ws + 184811520);
  float*  lamp  = (float*) (ws + 184844288);

  ushort* aT   = slotA;               // trans_norm .. decomp2
  ushort* xT   = slotE;               // trans_norm .. postattn
  ushort* Vm   = slotB;               // V gemm .. k_bt
  ushort* VT   = slotD;               // k_bt .. PV
  ushort* trT  = slotB;               // decomp2 .. Q-proj
  ushort* seT  = slotC;               // decomp2 .. K-proj
  ushort* K12  = slotA;               // [8192,4096] spans A+B
  float*  scr  = (float*)slotC;       // scores [2][16][512][512] f32
  ushort* Pm   = slotB;               // PV out [B,C,S]
  ushort* attn = slotC;               // postattn .. FFN2b
  ushort* hbuf = slotA;               // postattn .. FFN1b
  ushort* ff1T = slotB;               // [8192,2048]
  ushort* ff2T = slotD;               // [2048,8192]
  ushort* ffo  = slotE;               // final attn+ffo (xT dead)
  ushort* wsl  = slotF;               // vwT/q12T/k12T/dmat
  ushort* dmat = slotF;
  ushort* Qm   = (ushort*)d_out;      // [8192,4096] bf16 (dead after scores)
  ushort* H1   = (ushort*)d_out;      // [8192,4096] bf16 per FFN half

  const dim3 blk256(256), blk512(512), blkT(32, 8);

  // seq-axis rmsnorm + transpose
  k_rms_part<<<dim3(2, 8, B_), blk256, 0, stream>>>(x, part);
  k_rms_fin<<<dim3(32), blk256, 0, stream>>>(part, rms1);
  k_trans_norm<<<dim3(64, 16, B_), blkT, 0, stream>>>(x, rms1, ln_attn, aT, xT);

  // V path
  k_wtrans<<<dim3(64, 64), blkT, 0, stream>>>(v_w, wsl, 2048, 2048, 0);
  gemm256<1><<<dim3(32, 8), blk512, 0, stream>>>(aT, wsl, Vm, v_b, nullptr, 2048, 2048, 2048, 2048);
  k_bt<<<dim3(16, 64, B_), blkT, 0, stream>>>(Vm, VT, 512, 2048);

  // decompose (fused trend+seasonal, one read pass)
  k_decomp2<<<dim3(65536), blk256, 0, stream>>>(aT, trT, seT);

  // trend -> Q (d_out)
  k_wtrans<<<dim3(64, 128), blkT, 0, stream>>>(q12_w, wsl, 2048, 4096, 0);
  gemm256<1><<<dim3(32, 16), blk512, 0, stream>>>(trT, wsl, Qm, q12_b, nullptr, 2048, 2048, 2048, 4096);

  // seasonal -> K12 (A+B)
  k_lambda<<<dim3(1), blk256, 0, stream>>>(lq1, lk1, lq2, lk2, lamp);
  k_wtrans<<<dim3(64, 128), blkT, 0, stream>>>(k12_w, wsl, 2048, 4096, 0);
  gemm256<1><<<dim3(32, 16), blk512, 0, stream>>>(seT, wsl, K12, k12_b, nullptr, 2048, 2048, 2048, 4096);

  // scores (legacy 128^2, z = half*16 + b) -> scr[half][b][512][512]
  gemm_nt<0><<<dim3(4, 4, 32), blk256, 0, stream>>>(Qm, K12, scr, 2048, 4096, 4096, 512,
                                                    512L * 4096, 512L * 4096, 512L * 512,
                                                    2048L, 2048L, SCALE_F);

  // softmax -> dmat, PV -> Pm
  k_softmax<<<dim3(8192), blk256, 0, stream>>>(scr, scr + 4194304, lamp, dmat);
  gemm_nt<3><<<dim3(4, 16, B_), blk256, 0, stream>>>(dmat, VT, Pm, 512, 512, 512, 2048,
                                                     512L * 512, 2048L * 512, 512L * 2048,
                                                     0, 0, 1.f);

  // post-attn fused norms: attn->C, hbuf->A
  k_postattn<<<dim3(8192), blk256, 0, stream>>>(Pm, xT, norm_w, ln_ff, attn, hbuf);

  // FFN weights: ff1T->B, ff2T->D
  k_wtrans<<<dim3(64, 256), blkT, 0, stream>>>(ff_w1, ff1T, 2048, 8192, 0);
  k_wtrans<<<dim3(256, 64), blkT, 0, stream>>>(ff_w2, ff2T, 8192, 2048, 0);

  // FFN in 2 N-halves of H, full M=8192 each:
  //   H1 = gelu(hbuf @ ff1T_half + b1)             [8192 x 4096] -> d_out
  //   ffo = H1 @ ff2T_khalf (+ b2 + attn on 2nd)   [8192 x 2048]
  gemm256<2><<<dim3(32, 16), blk512, 0, stream>>>(hbuf, ff1T, H1, ff_b1, nullptr,
                                                  2048, 2048, 2048, 4096);
  gemm256<3><<<dim3(32, 8), blk512, 0, stream>>>(H1, ff2T, ffo, nullptr, nullptr,
                                                 4096, 4096, 8192, 2048);
  gemm256<2><<<dim3(32, 16), blk512, 0, stream>>>(hbuf, ff1T + (size_t)4096 * 2048, H1,
                                                  ff_b1 + 4096, nullptr, 2048, 2048, 2048, 4096);
  gemm256<4><<<dim3(32, 8), blk512, 0, stream>>>(H1, ff2T + 4096, ffo, ff_b2, attn,
                                                 4096, 4096, 8192, 2048);

  // out = x + (attn + ffo)^T
  k_final2<<<dim3(64, 16, B_), blkT, 0, stream>>>(x, ffo, out);
}

// Round 11
// 1182.750 us; speedup vs baseline: 1.1848x; 1.0375x over previous
//
#include <hip/hip_runtime.h>
#include <hip/hip_bf16.h>

#define B_ 16
#define S_ 2048
#define C_ 512
#define H_ 8192

#define LAMBDA_INIT_F 0.3555090675909693f
#define ONE_M_LI_F    0.6444909324090307f
#define SCALE_F       0.14865088937534013f

using bf16x8 = __attribute__((ext_vector_type(8))) short;
using f32x4  = __attribute__((ext_vector_type(4))) float;

__device__ __forceinline__ float b2f(ushort u) {
  union { unsigned u; float f; } x; x.u = ((unsigned)u) << 16; return x.f;
}
__device__ __forceinline__ ushort f2b(float f) {
  union { float f; unsigned u; } x; x.f = f;
  unsigned r = x.u + 0x7fffu + ((x.u >> 16) & 1u);
  return (ushort)(r >> 16);
}

__device__ __forceinline__ void load_lds16(const void* g, void* s) {
  __builtin_amdgcn_global_load_lds((const __attribute__((address_space(1))) void*)g,
                                   (__attribute__((address_space(3))) void*)s,
                                   16, 0, 0);
}

#define WAITV8() asm volatile("s_waitcnt vmcnt(8)" ::: "memory")
#define WAITV4() asm volatile("s_waitcnt vmcnt(4)" ::: "memory")
#define WAITV0() asm volatile("s_waitcnt vmcnt(0)" ::: "memory")
// lgkm wait needs sched_barrier: hipcc hoists register-only MFMA past inline-asm waits (rule 18)
#define WAITL0() do { asm volatile("s_waitcnt lgkmcnt(0)" ::: "memory"); __builtin_amdgcn_sched_barrier(0); } while (0)
#define BAR()    __builtin_amdgcn_s_barrier()

// ================= 256x256 GEMM, fat-phase ring + 2D XCD chunking (bf16 NT) =============
// R10-verified (best measured). EPI: 1 acc+bias | 2 gelu(acc+bias) | 3 acc | 4 Cold+acc+bias+add
template <int EPI>
__global__ __launch_bounds__(512, 1) void gemm256(
    const ushort* __restrict__ A, const ushort* __restrict__ Bt,
    ushort* __restrict__ C, const float* __restrict__ bias,
    const ushort* __restrict__ addm,
    int K, int lda, int ldb, int ldc)
{
  __shared__ ushort lds[65536];  // 4 slots x (A 8192 + B 8192) ushorts
  const int t = threadIdx.x, w = t >> 6, lane = t & 63;
  const int fr = lane & 15, khl = lane >> 4;
  const int wr = w >> 2, wc = w & 3;

  // 2D XCD chunking: gx == 32 at all call sites; gy in {8, 16}
  const int gx = gridDim.x, gy = gridDim.y;
  const int id = blockIdx.y * gx + blockIdx.x;
  const int xcd = id & 7, l = id >> 3;
  const int tnb = (gy == 16) ? 3 : 2;          // log2(tn), tn = gy/2
  const int lm = l >> tnb, ln = l & ((1 << tnb) - 1);
  const int m0 = ((xcd & 3) * 8 + lm) * 256;
  const int n0 = ((xcd >> 2) * (1 << tnb) + ln) * 256;

  // staging source (pre-swizzled so linear LDS write == swizzled layout; R5-verified pair)
  const int sl    = (t & 7) ^ ((t >> 3) & 7);
  const int rbase = ((t >> 3) << 1) + (sl >> 2);
  const int khs   = sl & 3;
  const size_t aoff = (size_t)(m0 + rbase) * lda + khs * 8;
  const size_t boff = (size_t)(n0 + rbase) * ldb + khs * 8;
  const size_t jstA = (size_t)128 * lda, jstB = (size_t)128 * ldb;

  // ds_read offsets within a unit (ushort units)
  int ao[8], bo[4];
#pragma unroll
  for (int m = 0; m < 8; ++m) {
    const int row = wr * 128 + m * 16 + fr, dr = row >> 1;
    const int so = (((row & 1) << 2) + khl) ^ (dr & 7);
    ao[m] = dr * 64 + so * 8;
  }
#pragma unroll
  for (int n = 0; n < 4; ++n) {
    const int row = wc * 64 + n * 16 + fr, dr = row >> 1;
    const int so = (((row & 1) << 2) + khl) ^ (dr & 7);
    bo[n] = 8192 + dr * 64 + so * 8;
  }

  f32x4 acc[8][4] = {};
  const int U = K >> 5;   // k-32 units; requires U >= 4

#define STAGE_U(u) do { \
    const ushort* sa_ = A  + aoff + (size_t)(u) * 32; \
    const ushort* sb_ = Bt + boff + (size_t)(u) * 32; \
    ushort* da_ = &lds[((u) & 3) * 16384 + w * 512]; \
    load_lds16(sa_, da_); load_lds16(sa_ + jstA, da_ + 4096); \
    load_lds16(sb_, da_ + 8192); load_lds16(sb_ + jstB, da_ + 12288); } while (0)
#define LDFRAG(u) do { const int sb_ = ((u) & 3) * 16384; \
    _Pragma("unroll") for (int m_ = 0; m_ < 8; ++m_) af[m_] = *(const bf16x8*)&lds[sb_ + ao[m_]]; \
    _Pragma("unroll") for (int n_ = 0; n_ < 4; ++n_) bg[n_] = *(const bf16x8*)&lds[sb_ + bo[n_]]; } while (0)
#define MFMA32() do { __builtin_amdgcn_s_setprio(1); \
    _Pragma("unroll") for (int m_ = 0; m_ < 8; ++m_) \
    _Pragma("unroll") for (int n_ = 0; n_ < 4; ++n_) \
      acc[m_][n_] = __builtin_amdgcn_mfma_f32_16x16x32_bf16(af[m_], bg[n_], acc[m_][n_], 0, 0, 0); \
    __builtin_amdgcn_s_setprio(0); } while (0)

  // prologue: stage units 0,1,2 (12 loads); retire unit 0 (vmcnt 12 -> 8)
  STAGE_U(0); STAGE_U(1); STAGE_U(2);
  WAITV8(); BAR();

  bf16x8 af[8], bg[4];
#pragma unroll 4
  for (int u = 0; u <= U - 4; ++u) {
    LDFRAG(u);
    STAGE_U(u + 3);
    WAITL0();
    MFMA32();
    WAITV8();   // retire unit u+1 (outstanding: u+1,u+2,u+3 = 12 -> 8)
    BAR();
  }
  { // phase U-3: no stage
    LDFRAG(U - 3);
    WAITL0();
    MFMA32();
    WAITV4();
    BAR();
  }
  { // phase U-2
    LDFRAG(U - 2);
    WAITL0();
    MFMA32();
    WAITV0();
    BAR();
  }
  { // phase U-1: all landed
    LDFRAG(U - 1);
    WAITL0();
    MFMA32();
  }
#undef STAGE_U
#undef LDFRAG
#undef MFMA32

  // epilogue: C/D col=lane&15, row=(lane>>4)*4+reg  [m89-verified]
  const int r0 = khl * 4;
#pragma unroll
  for (int m = 0; m < 8; ++m)
#pragma unroll
    for (int nf = 0; nf < 4; ++nf) {
      const int gr = m0 + wr * 128 + m * 16 + r0;
      const int gc = n0 + wc * 64 + nf * 16 + fr;
      const float bb = (EPI == 3) ? 0.f : bias[gc];
#pragma unroll
      for (int r = 0; r < 4; ++r) {
        const size_t idx = (size_t)(gr + r) * ldc + gc;
        float v = acc[m][nf][r];
        if constexpr (EPI == 1) v += bb;
        if constexpr (EPI == 2) { v += bb; v = 0.5f * v * (1.f + erff(v * 0.7071067811865475f)); }
        if constexpr (EPI == 4) v += bb + b2f(addm[idx]) + b2f(C[idx]);
        C[idx] = f2b(v);
      }
    }
}

// ================= legacy 128x128 GEMM =================
// z-decode: zb=z&15, zh=z>>4; A += zb*sA+zh*sA2; Bt += zb*sB+zh*sB2; C += z*sC
// EPI 0: f32 acc*alpha | 3: bf16 acc*alpha | 5: bf16 acc + bias[row]
template <int EPI>
__global__ __launch_bounds__(256, 2) void gemm_nt(
    const ushort* __restrict__ Aall, const ushort* __restrict__ Ball,
    void* __restrict__ Call, int K, int lda, int ldb, int ldc,
    long sA, long sB, long sC, long sA2, long sB2, float alpha,
    const float* __restrict__ bias)
{
  __shared__ ushort lA[4096];
  __shared__ ushort lB[4096];
  const int t = threadIdx.x;
  const int m0 = blockIdx.x * 128, n0 = blockIdx.y * 128;
  const int zb = blockIdx.z & 15, zh = blockIdx.z >> 4;
  const ushort* A  = Aall + (size_t)zb * sA + (size_t)zh * sA2;
  const ushort* Bt = Ball + (size_t)zb * sB + (size_t)zh * sB2;
  const int lane = t & 63;
  const int wave = t >> 6;
  const int wm = (wave >> 1) * 64, wn = (wave & 1) * 64;
  const int fr = lane & 15, kh = lane >> 4;
  f32x4 acc[4][4] = {};
  const int srow = t >> 2;
  const int scol = (t & 3) * 8;
  const size_t ar0 = (size_t)(m0 + srow) * lda + scol;
  const size_t ar1 = (size_t)(m0 + 64 + srow) * lda + scol;
  const size_t br0 = (size_t)(n0 + srow) * ldb + scol;
  const size_t br1 = (size_t)(n0 + 64 + srow) * ldb + scol;
  const int wbase = wave * 512;

  for (int k0 = 0; k0 < K; k0 += 32) {
    __syncthreads();
    load_lds16(A + ar0 + k0,  &lA[wbase]);
    load_lds16(A + ar1 + k0,  &lA[2048 + wbase]);
    load_lds16(Bt + br0 + k0, &lB[wbase]);
    load_lds16(Bt + br1 + k0, &lB[2048 + wbase]);
    __syncthreads();
    bf16x8 af[4], bg[4];
#pragma unroll
    for (int i = 0; i < 4; ++i)
      af[i] = *(const bf16x8*)&lA[(wm + i * 16 + fr) * 32 + kh * 8];
#pragma unroll
    for (int j = 0; j < 4; ++j)
      bg[j] = *(const bf16x8*)&lB[(wn + j * 16 + fr) * 32 + kh * 8];
#pragma unroll
    for (int i = 0; i < 4; ++i)
#pragma unroll
      for (int j = 0; j < 4; ++j)
        acc[i][j] = __builtin_amdgcn_mfma_f32_16x16x32_bf16(af[i], bg[j], acc[i][j], 0, 0, 0);
  }

  const int r0 = kh * 4;
  if constexpr (EPI == 0) {
    float* C = (float*)Call + (size_t)blockIdx.z * sC;
#pragma unroll
    for (int i = 0; i < 4; ++i)
#pragma unroll
      for (int j = 0; j < 4; ++j) {
        const int gr = m0 + wm + i * 16 + r0;
        const int gc = n0 + wn + j * 16 + fr;
#pragma unroll
        for (int r = 0; r < 4; ++r)
          C[(size_t)(gr + r) * ldc + gc] = acc[i][j][r] * alpha;
      }
  } else {
    ushort* C = (ushort*)Call + (size_t)blockIdx.z * sC;
#pragma unroll
    for (int i = 0; i < 4; ++i)
#pragma unroll
      for (int j = 0; j < 4; ++j) {
        const int gr = m0 + wm + i * 16 + r0;
        const int gc = n0 + wn + j * 16 + fr;
#pragma unroll
        for (int r = 0; r < 4; ++r) {
          float v = acc[i][j][r];
          if constexpr (EPI == 3) v *= alpha;
          if constexpr (EPI == 5) v += bias[gr + r];
          C[(size_t)(gr + r) * ldc + gc] = f2b(v);
        }
      }
  }
}

// ---------------- reductions ----------------
__device__ __forceinline__ float block_sum(float v, float* red) {
#pragma unroll
  for (int o = 32; o > 0; o >>= 1) v += __shfl_down(v, o, 64);
  __syncthreads();
  if ((threadIdx.x & 63) == 0) red[threadIdx.x >> 6] = v;
  __syncthreads();
  return red[0] + red[1] + red[2] + red[3];
}
__device__ __forceinline__ float block_max(float v, float* red) {
#pragma unroll
  for (int o = 32; o > 0; o >>= 1) v = fmaxf(v, __shfl_down(v, o, 64));
  __syncthreads();
  if ((threadIdx.x & 63) == 0) red[threadIdx.x >> 6] = v;
  __syncthreads();
  return fmaxf(fmaxf(red[0], red[1]), fmaxf(red[2], red[3]));
}

// ---------------- elementwise / transpose kernels ----------------
__global__ __launch_bounds__(256) void k_rms_part(const float* __restrict__ x, float* __restrict__ part) {
  const int c = blockIdx.x * 256 + threadIdx.x;
  const int sl = blockIdx.y;
  const int b = blockIdx.z;
  const float* p = x + (size_t)b * S_ * C_ + c;
  const int s0 = sl * 256;
  float s = 0.f;
  for (int i = 0; i < 256; ++i) { float v = p[(size_t)(s0 + i) * C_]; s += v * v; }
  part[((size_t)b * C_ + c) * 8 + sl] = s;
}
__global__ __launch_bounds__(256) void k_rms_fin(const float* __restrict__ part, float* __restrict__ rms1) {
  const int i = blockIdx.x * 256 + threadIdx.x;
  const float* p = part + (size_t)i * 8;
  float s = 0.f;
#pragma unroll
  for (int j = 0; j < 8; ++j) s += p[j];
  rms1[i] = rsqrtf(s * (1.f / S_) + 1e-8f);
}

__global__ __launch_bounds__(256) void k_trans_norm(const float* __restrict__ x, const float* __restrict__ rms1,
                                                    const float* __restrict__ w,
                                                    ushort* __restrict__ aT, ushort* __restrict__ xT) {
  __shared__ float tile[32][33];
  const int s0 = blockIdx.x * 32, c0 = blockIdx.y * 32, b = blockIdx.z;
  const int tx = threadIdx.x, ty = threadIdx.y;
  const float* xb = x + (size_t)b * S_ * C_;
#pragma unroll
  for (int r = 0; r < 4; ++r) {
    const int s = ty + 8 * r;
    tile[s][tx] = xb[(size_t)(s0 + s) * C_ + c0 + tx];
  }
  __syncthreads();
#pragma unroll
  for (int r = 0; r < 4; ++r) {
    const int c = ty + 8 * r;
    const float v = tile[tx][c];
    const float rm = rms1[b * C_ + c0 + c];
    const size_t o = ((size_t)b * C_ + c0 + c) * S_ + s0 + tx;
    xT[o] = f2b(v);
    aT[o] = f2b(v * rm * w[s0 + tx]);
  }
}

__global__ __launch_bounds__(256) void k_wtrans(const float* __restrict__ W, ushort* __restrict__ WT,
                                                int Kd, int Ndstride, int n_base) {
  __shared__ float tile[32][33];
  const int k0 = blockIdx.x * 32, n0 = blockIdx.y * 32;
  const int tx = threadIdx.x, ty = threadIdx.y;
#pragma unroll
  for (int r = 0; r < 4; ++r) {
    const int k = ty + 8 * r;
    tile[k][tx] = W[(size_t)(k0 + k) * Ndstride + n_base + n0 + tx];
  }
  __syncthreads();
#pragma unroll
  for (int r = 0; r < 4; ++r) {
    const int n = ty + 8 * r;
    WT[(size_t)(n0 + n) * Kd + k0 + tx] = f2b(tile[tx][n]);
  }
}

// flat f32 -> bf16 convert (8 elems/thread)
__global__ __launch_bounds__(256) void k_convert(const float* __restrict__ in, ushort* __restrict__ out) {
  const size_t i = ((size_t)blockIdx.x * 256 + threadIdx.x) * 8;
  const f32x4 v0 = *(const f32x4*)(in + i);
  const f32x4 v1 = *(const f32x4*)(in + i + 4);
  bf16x8 o;
#pragma unroll
  for (int j = 0; j < 4; ++j) { o[j] = (short)f2b(v0[j]); o[4 + j] = (short)f2b(v1[j]); }
  *(bf16x8*)(out + i) = o;
}

// vv[s]      = sum_t k12_w[s,t]      * q12_b[t]       (t < 2048)
// vv[2048+s] = sum_t k12_w[s,2048+t] * q12_b[2048+t]
__global__ __launch_bounds__(256) void k_matvec(const float* __restrict__ kw, const float* __restrict__ qb,
                                                float* __restrict__ vv) {
  __shared__ float red[4];
  const int s = blockIdx.x;
  const float* row = kw + (size_t)s * 4096;
  const int t = threadIdx.x;
  float s1 = 0.f, s2 = 0.f;
  for (int i = t; i < 2048; i += 256) { s1 += row[i] * qb[i]; s2 += row[2048 + i] * qb[2048 + i]; }
  s1 = block_sum(s1, red);
  s2 = block_sum(s2, red);
  if (t == 0) { vv[s] = s1; vv[2048 + s] = s2; }
}

// rvec[r] = SCALE * sum_s seT[r,s]*vv[s] ; rvec[8192+r] = SCALE * sum_s seT[r,s]*vv[2048+s]
__global__ __launch_bounds__(256) void k_gemv(const ushort* __restrict__ seT, const float* __restrict__ vv,
                                              float* __restrict__ rvec) {
  __shared__ float red[4];
  const int r = blockIdx.x;
  const ushort* row = seT + (size_t)r * 2048;
  const int t = threadIdx.x;
  float s1 = 0.f, s2 = 0.f;
  for (int i = t; i < 2048; i += 256) {
    const float sv = b2f(row[i]);
    s1 += sv * vv[i]; s2 += sv * vv[2048 + i];
  }
  s1 = block_sum(s1, red);
  s2 = block_sum(s2, red);
  if (t == 0) { rvec[r] = SCALE_F * s1; rvec[8192 + r] = SCALE_F * s2; }
}

__device__ __forceinline__ float trend5(const ushort* p, int s) {
  float sum = 0.f;
#pragma unroll
  for (int d = -2; d <= 2; ++d) {
    int ss = s + d; ss = ss < 0 ? 0 : (ss > S_ - 1 ? S_ - 1 : ss);
    sum += b2f(p[ss]);
  }
  return sum * 0.2f;
}
__global__ __launch_bounds__(256) void k_decomp2(const ushort* __restrict__ aT,
                                                 ushort* __restrict__ trT, ushort* __restrict__ seT) {
  const size_t i = (size_t)blockIdx.x * 256 + threadIdx.x;
  const int s = (int)(i & (S_ - 1));
  const ushort* p = aT + (i - s);
  const float tr = trend5(p, s);
  trT[i] = f2b(tr);
  seT[i] = f2b(b2f(p[s]) - tr);
}

__global__ __launch_bounds__(256) void k_lambda(const float* __restrict__ lq1, const float* __restrict__ lk1,
                                                const float* __restrict__ lq2, const float* __restrict__ lk2,
                                                float* __restrict__ lam) {
  __shared__ float r1[4], r2[4];
  const int t = threadIdx.x;
  float s1 = 0.f, s2 = 0.f;
  for (int i = t; i < S_; i += 256) { s1 += lq1[i] * lk1[i]; s2 += lq2[i] * lk2[i]; }
#pragma unroll
  for (int o = 32; o > 0; o >>= 1) { s1 += __shfl_down(s1, o, 64); s2 += __shfl_down(s2, o, 64); }
  if ((t & 63) == 0) { r1[t >> 6] = s1; r2[t >> 6] = s2; }
  __syncthreads();
  if (t == 0) {
    const float a = r1[0] + r1[1] + r1[2] + r1[3];
    const float b = r2[0] + r2[1] + r2[2] + r2[3];
    *lam = expf(a) - expf(b) + LAMBDA_INIT_F;
  }
}

// d = softmax(a1 + rvec1) - lam*softmax(a2 + rvec2); rvec indexed by column j (bias rank-1 term)
__global__ __launch_bounds__(256) void k_softmax(const float* __restrict__ a1, const float* __restrict__ a2,
                                                 const float* __restrict__ lamp, const float* __restrict__ rvec,
                                                 ushort* __restrict__ dm) {
  __shared__ float red[4];
  const size_t row = blockIdx.x;
  const int jb = ((int)row >> 9) << 9;   // b*512
  const float* p1 = a1 + row * 512;
  const float* p2 = a2 + row * 512;
  const int t = threadIdx.x;
  const float v1a = p1[t] + rvec[jb + t],        v1b = p1[t + 256] + rvec[jb + t + 256];
  const float v2a = p2[t] + rvec[8192 + jb + t], v2b = p2[t + 256] + rvec[8192 + jb + t + 256];
  const float m1 = block_max(fmaxf(v1a, v1b), red);
  const float m2 = block_max(fmaxf(v2a, v2b), red);
  const float e1a = expf(v1a - m1), e1b = expf(v1b - m1);
  const float e2a = expf(v2a - m2), e2b = expf(v2b - m2);
  const float s1 = block_sum(e1a + e1b, red);
  const float s2 = block_sum(e2a + e2b, red);
  const float i1 = 1.f / s1, i2 = (*lamp) / s2;
  ushort* o = dm + row * 512;
  o[t]       = f2b(e1a * i1 - e2a * i2);
  o[t + 256] = f2b(e1b * i1 - e2b * i2);
}

__global__ __launch_bounds__(256) void k_postattn(const ushort* __restrict__ P, const ushort* __restrict__ xT,
                                                  const float* __restrict__ norm_w, const float* __restrict__ ln_ff_w,
                                                  ushort* __restrict__ attn, ushort* __restrict__ h) {
  __shared__ float red[4];
  const size_t row = blockIdx.x;
  const ushort* p = P + row * S_;
  const int t = threadIdx.x;
  float v[8]; float ss = 0.f;
#pragma unroll
  for (int i = 0; i < 8; ++i) { v[i] = b2f(p[t + 256 * i]); ss += v[i] * v[i]; }
  ss = block_sum(ss, red);
  const float inv = rsqrtf(ss * (1.f / S_) + 1e-8f);
  const ushort* xr = xT + row * S_;
  ushort* ar = attn + row * S_;
  float x2[8]; float ss2 = 0.f;
#pragma unroll
  for (int i = 0; i < 8; ++i) {
    const int s = t + 256 * i;
    const float at = v[i] * inv * norm_w[s] * ONE_M_LI_F;
    ar[s] = f2b(at);
    const float xx = b2f(xr[s]) + at;
    x2[i] = xx; ss2 += xx * xx;
  }
  ss2 = block_sum(ss2, red);
  const float inv2 = rsqrtf(ss2 * (1.f / S_) + 1e-8f);
  ushort* hr = h + row * S_;
#pragma unroll
  for (int i = 0; i < 8; ++i) { const int s = t + 256 * i; hr[s] = f2b(x2[i] * inv2 * ln_ff_w[s]); }
}

// out[b,s,c] = x[b,s,c] + sumT[b,c,s]
__global__ __launch_bounds__(256) void k_final2(const float* __restrict__ x, const ushort* __restrict__ sumT,
                                                float* __restrict__ out) {
  __shared__ float tile[32][33];
  const int s0 = blockIdx.x * 32, c0 = blockIdx.y * 32, b = blockIdx.z;
  const int tx = threadIdx.x, ty = threadIdx.y;
#pragma unroll
  for (int r = 0; r < 4; ++r) {
    const int c = ty + 8 * r;
    tile[c][tx] = b2f(sumT[((size_t)b * C_ + c0 + c) * S_ + s0 + tx]);
  }
  __syncthreads();
#pragma unroll
  for (int r = 0; r < 4; ++r) {
    const int s = ty + 8 * r;
    const size_t o = ((size_t)b * S_ + s0 + s) * C_ + c0 + tx;
    out[o] = x[o] + tile[tx][s];
  }
}

__global__ void k_probe(float* out, float v) { out[0] = v; }

// ---------------- launch ----------------
extern "C" void kernel_launch(void* const* d_in, const int* in_sizes, int n_in,
                              void* d_out, int out_size, void* d_ws, size_t ws_size,
                              hipStream_t stream) {
  const float* x       = (const float*)d_in[0];
  const float* ln_attn = (const float*)d_in[1];
  const float* q12_w   = (const float*)d_in[2];
  const float* q12_b   = (const float*)d_in[3];
  const float* k12_w   = (const float*)d_in[4];
  const float* k12_b   = (const float*)d_in[5];
  const float* v_w     = (const float*)d_in[6];
  const float* v_b     = (const float*)d_in[7];
  const float* lq1     = (const float*)d_in[8];
  const float* lk1     = (const float*)d_in[9];
  const float* lq2     = (const float*)d_in[10];
  const float* lk2     = (const float*)d_in[11];
  const float* norm_w  = (const float*)d_in[12];
  const float* ln_ff   = (const float*)d_in[13];
  const float* ff_w1   = (const float*)d_in[14];
  const float* ff_b1   = (const float*)d_in[15];
  const float* ff_w2   = (const float*)d_in[16];
  const float* ff_b2   = (const float*)d_in[17];
  float* out = (float*)d_out;

  if (ws_size < 184844544ull) {
    k_probe<<<1, 1, 0, stream>>>(out, (float)(ws_size >> 20));
    return;
  }

  char* ws = (char*)d_ws;
  ushort* slotA = (ushort*)(ws + 0);
  ushort* slotB = (ushort*)(ws + 33554432);
  ushort* slotC = (ushort*)(ws + 67108864);
  ushort* slotD = (ushort*)(ws + 100663296);
  ushort* slotE = (ushort*)(ws + 134217728);
  ushort* slotF = (ushort*)(ws + 167772160);
  float*  part  = (float*) (ws + 184549376);
  float*  rms1  = (float*) (ws + 184811520);
  float*  lamp  = (float*) (ws + 184844288);

  // liveness-packed aliases
  ushort* aT   = slotA;                          // trans_norm .. decomp2 (+V-direct)
  ushort* k12c = slotA;                          // convert .. M12T
  ushort* T12s = slotA;                          // T1 / T2 (33.5 MB)
  ushort* hbuf = slotA;                          // postattn .. FFN1
  ushort* trT  = slotB;                          // decomp2 .. T2-proj
  ushort* Pm   = slotB;                          // PV out
  ushort* ff1T = slotB;
  ushort* seT  = slotC;                          // decomp2 .. a2 (+gemv)
  ushort* attn = slotC;
  ushort* VT   = slotD;                          // V-direct .. PV
  ushort* ff2T = slotD;
  ushort* xT   = slotE;                          // trans_norm .. postattn
  ushort* ffo  = slotE;
  ushort* wsl  = slotF;                          // vwT, then q12c
  ushort* q12c = slotF;
  ushort* dmat = slotF;                          // softmax out (8.4 MB)
  float*  vvb  = (float*)(ws + 167772160 + 12582912);  // F+12MB: vv[4096]
  float*  rvec = vvb + 4096;                           // rvec[16384]
  ushort* M12T = (ushort*)d_out;                 // [4096,2048] bf16 (16.78 MB)
  float*  scr  = (float*)((char*)d_out + 16777216);    // [2][16][512][512] f32 (33.5 MB)
  ushort* H1   = (ushort*)d_out;                 // FFN half (67 MB; M12T/scr dead)

  const dim3 blk256(256), blk512(512), blkT(32, 8);

  // seq-axis rmsnorm + transpose
  k_rms_part<<<dim3(2, 8, B_), blk256, 0, stream>>>(x, part);
  k_rms_fin<<<dim3(32), blk256, 0, stream>>>(part, rms1);
  k_trans_norm<<<dim3(64, 16, B_), blkT, 0, stream>>>(x, rms1, ln_attn, aT, xT);

  // V path, direct-transposed: VT[b][s][c] = sum_k v_w[k,s]*aT[b*512+c,k] + v_b[s]
  k_wtrans<<<dim3(64, 64), blkT, 0, stream>>>(v_w, wsl, 2048, 2048, 0);
  gemm_nt<5><<<dim3(16, 4, 16), blk256, 0, stream>>>(wsl, aT, VT, 2048, 2048, 2048, 512,
                                                     0, 1048576, 1048576, 0, 0, 1.f, v_b);

  // decompose (fused trend+seasonal)
  k_decomp2<<<dim3(65536), blk256, 0, stream>>>(aT, trT, seT);
  k_lambda<<<dim3(1), blk256, 0, stream>>>(lq1, lk1, lq2, lk2, lamp);

  // weight products: M12T[h][n][k] = sum_t q_hw[k,t]*k_hw[n,t]  (h = half)
  k_convert<<<dim3(4096), blk256, 0, stream>>>(q12_w, q12c);
  k_convert<<<dim3(4096), blk256, 0, stream>>>(k12_w, k12c);
  gemm_nt<3><<<dim3(16, 16, 2), blk256, 0, stream>>>(k12c, q12c, M12T, 2048, 4096, 4096, 2048,
                                                     2048, 2048, 4194304, 0, 0, 1.f, nullptr);

  // bias rank-1 term: vv = k_hw . q_hb ; rvec = SCALE * Se . vv
  k_matvec<<<dim3(2048), blk256, 0, stream>>>(k12_w, q12_b, vvb);
  k_gemv<<<dim3(8192), blk256, 0, stream>>>(seT, vvb, rvec);

  // T1 = Tr.M1 -> a1 ; T2 = Tr.M2 -> a2   (a_h = T_h.Se^T * SCALE)
  gemm256<3><<<dim3(32, 8), blk512, 0, stream>>>(trT, M12T, T12s, nullptr, nullptr,
                                                 2048, 2048, 2048, 2048);
  gemm_nt<0><<<dim3(4, 4, 16), blk256, 0, stream>>>(T12s, seT, scr, 2048, 2048, 2048, 512,
                                                    1048576, 1048576, 262144, 0, 0, SCALE_F, nullptr);
  gemm256<3><<<dim3(32, 8), blk512, 0, stream>>>(trT, M12T + 4194304, T12s, nullptr, nullptr,
                                                 2048, 2048, 2048, 2048);
  gemm_nt<0><<<dim3(4, 4, 16), blk256, 0, stream>>>(T12s, seT, scr + 4194304, 2048, 2048, 2048, 512,
                                                    1048576, 1048576, 262144, 0, 0, SCALE_F, nullptr);

  // softmax -> dmat, PV -> Pm
  k_softmax<<<dim3(8192), blk256, 0, stream>>>(scr, scr + 4194304, lamp, rvec, dmat);
  gemm_nt<3><<<dim3(4, 16, B_), blk256, 0, stream>>>(dmat, VT, Pm, 512, 512, 512, 2048,
                                                     262144, 1048576, 1048576, 0, 0, 1.f, nullptr);

  // post-attn fused norms: attn->C, hbuf->A
  k_postattn<<<dim3(8192), blk256, 0, stream>>>(Pm, xT, norm_w, ln_ff, attn, hbuf);

  // FFN weights: ff1T->B, ff2T->D
  k_wtrans<<<dim3(64, 256), blkT, 0, stream>>>(ff_w1, ff1T, 2048, 8192, 0);
  k_wtrans<<<dim3(256, 64), blkT, 0, stream>>>(ff_w2, ff2T, 8192, 2048, 0);

  // FFN in 2 N-halves of H, full M=8192 each
  gemm256<2><<<dim3(32, 16), blk512, 0, stream>>>(hbuf, ff1T, H1, ff_b1, nullptr,
                                                  2048, 2048, 2048, 4096);
  gemm256<3><<<dim3(32, 8), blk512, 0, stream>>>(H1, ff2T, ffo, nullptr, nullptr,
                                                 4096, 4096, 8192, 2048);
  gemm256<2><<<dim3(32, 16), blk512, 0, stream>>>(hbuf, ff1T + (size_t)4096 * 2048, H1,
                                                  ff_b1 + 4096, nullptr, 2048, 2048, 2048, 4096);
  gemm256<4><<<dim3(32, 8), blk512, 0, stream>>>(H1, ff2T + 4096, ffo, ff_b2, attn,
                                                 4096, 4096, 8192, 2048);

  // out = x + (attn + ffo)^T
  k_final2<<<dim3(64, 16, B_), blkT, 0, stream>>>(x, ffo, out);
}

// Round 12
// 1182.696 us; speedup vs baseline: 1.1848x; 1.0000x over previous
//
#include <hip/hip_runtime.h>
#include <hip/hip_bf16.h>

#define B_ 16
#define S_ 2048
#define C_ 512
#define H_ 8192

#define LAMBDA_INIT_F 0.3555090675909693f
#define ONE_M_LI_F    0.6444909324090307f
#define SCALE_F       0.14865088937534013f

using bf16x8 = __attribute__((ext_vector_type(8))) short;
using f32x4  = __attribute__((ext_vector_type(4))) float;

__device__ __forceinline__ float b2f(ushort u) {
  union { unsigned u; float f; } x; x.u = ((unsigned)u) << 16; return x.f;
}
__device__ __forceinline__ ushort f2b(float f) {
  union { float f; unsigned u; } x; x.f = f;
  unsigned r = x.u + 0x7fffu + ((x.u >> 16) & 1u);
  return (ushort)(r >> 16);
}

__device__ __forceinline__ void load_lds16(const void* g, void* s) {
  __builtin_amdgcn_global_load_lds((const __attribute__((address_space(1))) void*)g,
                                   (__attribute__((address_space(3))) void*)s,
                                   16, 0, 0);
}

#define WAITV8() asm volatile("s_waitcnt vmcnt(8)" ::: "memory")
#define WAITV4() asm volatile("s_waitcnt vmcnt(4)" ::: "memory")
#define WAITV0() asm volatile("s_waitcnt vmcnt(0)" ::: "memory")
// barrier with compiler memory-fence semantics (plain builtin lets ds_reads hoist across)
#define BARM()   asm volatile("s_barrier" ::: "memory")
#define BAR()    __builtin_amdgcn_s_barrier()

// ================= 256x256 GEMM, fat-phase ring + 2D XCD chunking (bf16 NT) =============
// R11 change: NO manual lgkmcnt before MFMA — ds_reads are compiler-visible, the compiler
// emits fine-grained counted lgkmcnt and interleaves read-returns with MFMAs (m97 behavior).
// Cross-wave staging hazard covered by counted vmcnt (asm, memory clobber) + BARM.
// EPI: 1 acc+bias | 2 gelu(acc+bias) | 3 acc | 4 Cold+acc+bias+add
template <int EPI>
__global__ __launch_bounds__(512, 1) void gemm256(
    const ushort* __restrict__ A, const ushort* __restrict__ Bt,
    ushort* __restrict__ C, const float* __restrict__ bias,
    const ushort* __restrict__ addm,
    int K, int lda, int ldb, int ldc)
{
  __shared__ ushort lds[65536];  // 4 slots x (A 8192 + B 8192) ushorts
  const int t = threadIdx.x, w = t >> 6, lane = t & 63;
  const int fr = lane & 15, khl = lane >> 4;
  const int wr = w >> 2, wc = w & 3;

  // 2D XCD chunking: gx == 32 at all call sites; gy in {8, 16}
  const int gx = gridDim.x, gy = gridDim.y;
  const int id = blockIdx.y * gx + blockIdx.x;
  const int xcd = id & 7, l = id >> 3;
  const int tnb = (gy == 16) ? 3 : 2;          // log2(tn), tn = gy/2
  const int lm = l >> tnb, ln = l & ((1 << tnb) - 1);
  const int m0 = ((xcd & 3) * 8 + lm) * 256;
  const int n0 = ((xcd >> 2) * (1 << tnb) + ln) * 256;

  // staging source (pre-swizzled so linear LDS write == swizzled layout; R5-verified pair)
  const int sl    = (t & 7) ^ ((t >> 3) & 7);
  const int rbase = ((t >> 3) << 1) + (sl >> 2);
  const int khs   = sl & 3;
  const size_t aoff = (size_t)(m0 + rbase) * lda + khs * 8;
  const size_t boff = (size_t)(n0 + rbase) * ldb + khs * 8;
  const size_t jstA = (size_t)128 * lda, jstB = (size_t)128 * ldb;

  // ds_read offsets within a unit (ushort units)
  int ao[8], bo[4];
#pragma unroll
  for (int m = 0; m < 8; ++m) {
    const int row = wr * 128 + m * 16 + fr, dr = row >> 1;
    const int so = (((row & 1) << 2) + khl) ^ (dr & 7);
    ao[m] = dr * 64 + so * 8;
  }
#pragma unroll
  for (int n = 0; n < 4; ++n) {
    const int row = wc * 64 + n * 16 + fr, dr = row >> 1;
    const int so = (((row & 1) << 2) + khl) ^ (dr & 7);
    bo[n] = 8192 + dr * 64 + so * 8;
  }

  f32x4 acc[8][4] = {};
  const int U = K >> 5;   // k-32 units; requires U >= 4

#define STAGE_U(u) do { \
    const ushort* sa_ = A  + aoff + (size_t)(u) * 32; \
    const ushort* sb_ = Bt + boff + (size_t)(u) * 32; \
    ushort* da_ = &lds[((u) & 3) * 16384 + w * 512]; \
    load_lds16(sa_, da_); load_lds16(sa_ + jstA, da_ + 4096); \
    load_lds16(sb_, da_ + 8192); load_lds16(sb_ + jstB, da_ + 12288); } while (0)
#define LDFRAG(u) do { const int sb_ = ((u) & 3) * 16384; \
    _Pragma("unroll") for (int m_ = 0; m_ < 8; ++m_) af[m_] = *(const bf16x8*)&lds[sb_ + ao[m_]]; \
    _Pragma("unroll") for (int n_ = 0; n_ < 4; ++n_) bg[n_] = *(const bf16x8*)&lds[sb_ + bo[n_]]; } while (0)
#define MFMA32() do { __builtin_amdgcn_s_setprio(1); \
    _Pragma("unroll") for (int m_ = 0; m_ < 8; ++m_) \
    _Pragma("unroll") for (int n_ = 0; n_ < 4; ++n_) \
      acc[m_][n_] = __builtin_amdgcn_mfma_f32_16x16x32_bf16(af[m_], bg[n_], acc[m_][n_], 0, 0, 0); \
    __builtin_amdgcn_s_setprio(0); } while (0)

  // prologue: stage units 0,1,2 (12 loads); retire unit 0 (vmcnt 12 -> 8)
  STAGE_U(0); STAGE_U(1); STAGE_U(2);
  WAITV8(); BARM();

  bf16x8 af[8], bg[4];
#pragma unroll 4
  for (int u = 0; u <= U - 4; ++u) {
    LDFRAG(u);
    STAGE_U(u + 3);
    MFMA32();        // compiler inserts fine-grained lgkmcnt for af/bg dataflow
    WAITV8();        // retire unit u+1 (outstanding: u+1,u+2,u+3 = 12 -> 8)
    BARM();
  }
  { // phase U-3: no stage
    LDFRAG(U - 3);
    MFMA32();
    WAITV4();
    BARM();
  }
  { // phase U-2
    LDFRAG(U - 2);
    MFMA32();
    WAITV0();
    BARM();
  }
  { // phase U-1: all landed
    LDFRAG(U - 1);
    MFMA32();
  }
#undef STAGE_U
#undef LDFRAG
#undef MFMA32

  // epilogue: C/D col=lane&15, row=(lane>>4)*4+reg  [m89-verified]
  const int r0 = khl * 4;
#pragma unroll
  for (int m = 0; m < 8; ++m)
#pragma unroll
    for (int nf = 0; nf < 4; ++nf) {
      const int gr = m0 + wr * 128 + m * 16 + r0;
      const int gc = n0 + wc * 64 + nf * 16 + fr;
      const float bb = (EPI == 3) ? 0.f : bias[gc];
#pragma unroll
      for (int r = 0; r < 4; ++r) {
        const size_t idx = (size_t)(gr + r) * ldc + gc;
        float v = acc[m][nf][r];
        if constexpr (EPI == 1) v += bb;
        if constexpr (EPI == 2) { v += bb; v = 0.5f * v * (1.f + erff(v * 0.7071067811865475f)); }
        if constexpr (EPI == 4) v += bb + b2f(addm[idx]) + b2f(C[idx]);
        C[idx] = f2b(v);
      }
    }
}

// ================= legacy 128x128 GEMM =================
// z-decode: zb=z&15, zh=z>>4; A += zb*sA+zh*sA2; Bt += zb*sB+zh*sB2; C += z*sC
// EPI 0: f32 acc*alpha | 3: bf16 acc*alpha | 5: bf16 acc + bias[row]
template <int EPI>
__global__ __launch_bounds__(256, 2) void gemm_nt(
    const ushort* __restrict__ Aall, const ushort* __restrict__ Ball,
    void* __restrict__ Call, int K, int lda, int ldb, int ldc,
    long sA, long sB, long sC, long sA2, long sB2, float alpha,
    const float* __restrict__ bias)
{
  __shared__ ushort lA[4096];
  __shared__ ushort lB[4096];
  const int t = threadIdx.x;
  const int m0 = blockIdx.x * 128, n0 = blockIdx.y * 128;
  const int zb = blockIdx.z & 15, zh = blockIdx.z >> 4;
  const ushort* A  = Aall + (size_t)zb * sA + (size_t)zh * sA2;
  const ushort* Bt = Ball + (size_t)zb * sB + (size_t)zh * sB2;
  const int lane = t & 63;
  const int wave = t >> 6;
  const int wm = (wave >> 1) * 64, wn = (wave & 1) * 64;
  const int fr = lane & 15, kh = lane >> 4;
  f32x4 acc[4][4] = {};
  const int srow = t >> 2;
  const int scol = (t & 3) * 8;
  const size_t ar0 = (size_t)(m0 + srow) * lda + scol;
  const size_t ar1 = (size_t)(m0 + 64 + srow) * lda + scol;
  const size_t br0 = (size_t)(n0 + srow) * ldb + scol;
  const size_t br1 = (size_t)(n0 + 64 + srow) * ldb + scol;
  const int wbase = wave * 512;

  for (int k0 = 0; k0 < K; k0 += 32) {
    __syncthreads();
    load_lds16(A + ar0 + k0,  &lA[wbase]);
    load_lds16(A + ar1 + k0,  &lA[2048 + wbase]);
    load_lds16(Bt + br0 + k0, &lB[wbase]);
    load_lds16(Bt + br1 + k0, &lB[2048 + wbase]);
    __syncthreads();
    bf16x8 af[4], bg[4];
#pragma unroll
    for (int i = 0; i < 4; ++i)
      af[i] = *(const bf16x8*)&lA[(wm + i * 16 + fr) * 32 + kh * 8];
#pragma unroll
    for (int j = 0; j < 4; ++j)
      bg[j] = *(const bf16x8*)&lB[(wn + j * 16 + fr) * 32 + kh * 8];
#pragma unroll
    for (int i = 0; i < 4; ++i)
#pragma unroll
      for (int j = 0; j < 4; ++j)
        acc[i][j] = __builtin_amdgcn_mfma_f32_16x16x32_bf16(af[i], bg[j], acc[i][j], 0, 0, 0);
  }

  const int r0 = kh * 4;
  if constexpr (EPI == 0) {
    float* C = (float*)Call + (size_t)blockIdx.z * sC;
#pragma unroll
    for (int i = 0; i < 4; ++i)
#pragma unroll
      for (int j = 0; j < 4; ++j) {
        const int gr = m0 + wm + i * 16 + r0;
        const int gc = n0 + wn + j * 16 + fr;
#pragma unroll
        for (int r = 0; r < 4; ++r)
          C[(size_t)(gr + r) * ldc + gc] = acc[i][j][r] * alpha;
      }
  } else {
    ushort* C = (ushort*)Call + (size_t)blockIdx.z * sC;
#pragma unroll
    for (int i = 0; i < 4; ++i)
#pragma unroll
      for (int j = 0; j < 4; ++j) {
        const int gr = m0 + wm + i * 16 + r0;
        const int gc = n0 + wn + j * 16 + fr;
#pragma unroll
        for (int r = 0; r < 4; ++r) {
          float v = acc[i][j][r];
          if constexpr (EPI == 3) v *= alpha;
          if constexpr (EPI == 5) v += bias[gr + r];
          C[(size_t)(gr + r) * ldc + gc] = f2b(v);
        }
      }
  }
}

// ---------------- reductions ----------------
__device__ __forceinline__ float block_sum(float v, float* red) {
#pragma unroll
  for (int o = 32; o > 0; o >>= 1) v += __shfl_down(v, o, 64);
  __syncthreads();
  if ((threadIdx.x & 63) == 0) red[threadIdx.x >> 6] = v;
  __syncthreads();
  return red[0] + red[1] + red[2] + red[3];
}
__device__ __forceinline__ float block_max(float v, float* red) {
#pragma unroll
  for (int o = 32; o > 0; o >>= 1) v = fmaxf(v, __shfl_down(v, o, 64));
  __syncthreads();
  if ((threadIdx.x & 63) == 0) red[threadIdx.x >> 6] = v;
  __syncthreads();
  return fmaxf(fmaxf(red[0], red[1]), fmaxf(red[2], red[3]));
}

// ---------------- elementwise / transpose kernels ----------------
__global__ __launch_bounds__(256) void k_rms_part(const float* __restrict__ x, float* __restrict__ part) {
  const int c = blockIdx.x * 256 + threadIdx.x;
  const int sl = blockIdx.y;
  const int b = blockIdx.z;
  const float* p = x + (size_t)b * S_ * C_ + c;
  const int s0 = sl * 256;
  float s = 0.f;
  for (int i = 0; i < 256; ++i) { float v = p[(size_t)(s0 + i) * C_]; s += v * v; }
  part[((size_t)b * C_ + c) * 8 + sl] = s;
}
__global__ __launch_bounds__(256) void k_rms_fin(const float* __restrict__ part, float* __restrict__ rms1) {
  const int i = blockIdx.x * 256 + threadIdx.x;
  const float* p = part + (size_t)i * 8;
  float s = 0.f;
#pragma unroll
  for (int j = 0; j < 8; ++j) s += p[j];
  rms1[i] = rsqrtf(s * (1.f / S_) + 1e-8f);
}

__global__ __launch_bounds__(256) void k_trans_norm(const float* __restrict__ x, const float* __restrict__ rms1,
                                                    const float* __restrict__ w,
                                                    ushort* __restrict__ aT, ushort* __restrict__ xT) {
  __shared__ float tile[32][33];
  const int s0 = blockIdx.x * 32, c0 = blockIdx.y * 32, b = blockIdx.z;
  const int tx = threadIdx.x, ty = threadIdx.y;
  const float* xb = x + (size_t)b * S_ * C_;
#pragma unroll
  for (int r = 0; r < 4; ++r) {
    const int s = ty + 8 * r;
    tile[s][tx] = xb[(size_t)(s0 + s) * C_ + c0 + tx];
  }
  __syncthreads();
#pragma unroll
  for (int r = 0; r < 4; ++r) {
    const int c = ty + 8 * r;
    const float v = tile[tx][c];
    const float rm = rms1[b * C_ + c0 + c];
    const size_t o = ((size_t)b * C_ + c0 + c) * S_ + s0 + tx;
    xT[o] = f2b(v);
    aT[o] = f2b(v * rm * w[s0 + tx]);
  }
}

__global__ __launch_bounds__(256) void k_wtrans(const float* __restrict__ W, ushort* __restrict__ WT,
                                                int Kd, int Ndstride, int n_base) {
  __shared__ float tile[32][33];
  const int k0 = blockIdx.x * 32, n0 = blockIdx.y * 32;
  const int tx = threadIdx.x, ty = threadIdx.y;
#pragma unroll
  for (int r = 0; r < 4; ++r) {
    const int k = ty + 8 * r;
    tile[k][tx] = W[(size_t)(k0 + k) * Ndstride + n_base + n0 + tx];
  }
  __syncthreads();
#pragma unroll
  for (int r = 0; r < 4; ++r) {
    const int n = ty + 8 * r;
    WT[(size_t)(n0 + n) * Kd + k0 + tx] = f2b(tile[tx][n]);
  }
}

// flat f32 -> bf16 convert (8 elems/thread)
__global__ __launch_bounds__(256) void k_convert(const float* __restrict__ in, ushort* __restrict__ out) {
  const size_t i = ((size_t)blockIdx.x * 256 + threadIdx.x) * 8;
  const f32x4 v0 = *(const f32x4*)(in + i);
  const f32x4 v1 = *(const f32x4*)(in + i + 4);
  bf16x8 o;
#pragma unroll
  for (int j = 0; j < 4; ++j) { o[j] = (short)f2b(v0[j]); o[4 + j] = (short)f2b(v1[j]); }
  *(bf16x8*)(out + i) = o;
}

// vv[s]      = sum_t k12_w[s,t]      * q12_b[t]       (t < 2048)
// vv[2048+s] = sum_t k12_w[s,2048+t] * q12_b[2048+t]
__global__ __launch_bounds__(256) void k_matvec(const float* __restrict__ kw, const float* __restrict__ qb,
                                                float* __restrict__ vv) {
  __shared__ float red[4];
  const int s = blockIdx.x;
  const float* row = kw + (size_t)s * 4096;
  const int t = threadIdx.x;
  float s1 = 0.f, s2 = 0.f;
  for (int i = t; i < 2048; i += 256) { s1 += row[i] * qb[i]; s2 += row[2048 + i] * qb[2048 + i]; }
  s1 = block_sum(s1, red);
  s2 = block_sum(s2, red);
  if (t == 0) { vv[s] = s1; vv[2048 + s] = s2; }
}

// rvec[r] = SCALE * sum_s seT[r,s]*vv[s] ; rvec[8192+r] = SCALE * sum_s seT[r,s]*vv[2048+s]
__global__ __launch_bounds__(256) void k_gemv(const ushort* __restrict__ seT, const float* __restrict__ vv,
                                              float* __restrict__ rvec) {
  __shared__ float red[4];
  const int r = blockIdx.x;
  const ushort* row = seT + (size_t)r * 2048;
  const int t = threadIdx.x;
  float s1 = 0.f, s2 = 0.f;
  for (int i = t; i < 2048; i += 256) {
    const float sv = b2f(row[i]);
    s1 += sv * vv[i]; s2 += sv * vv[2048 + i];
  }
  s1 = block_sum(s1, red);
  s2 = block_sum(s2, red);
  if (t == 0) { rvec[r] = SCALE_F * s1; rvec[8192 + r] = SCALE_F * s2; }
}

__device__ __forceinline__ float trend5(const ushort* p, int s) {
  float sum = 0.f;
#pragma unroll
  for (int d = -2; d <= 2; ++d) {
    int ss = s + d; ss = ss < 0 ? 0 : (ss > S_ - 1 ? S_ - 1 : ss);
    sum += b2f(p[ss]);
  }
  return sum * 0.2f;
}
__global__ __launch_bounds__(256) void k_decomp2(const ushort* __restrict__ aT,
                                                 ushort* __restrict__ trT, ushort* __restrict__ seT) {
  const size_t i = (size_t)blockIdx.x * 256 + threadIdx.x;
  const int s = (int)(i & (S_ - 1));
  const ushort* p = aT + (i - s);
  const float tr = trend5(p, s);
  trT[i] = f2b(tr);
  seT[i] = f2b(b2f(p[s]) - tr);
}

__global__ __launch_bounds__(256) void k_lambda(const float* __restrict__ lq1, const float* __restrict__ lk1,
                                                const float* __restrict__ lq2, const float* __restrict__ lk2,
                                                float* __restrict__ lam) {
  __shared__ float r1[4], r2[4];
  const int t = threadIdx.x;
  float s1 = 0.f, s2 = 0.f;
  for (int i = t; i < S_; i += 256) { s1 += lq1[i] * lk1[i]; s2 += lq2[i] * lk2[i]; }
#pragma unroll
  for (int o = 32; o > 0; o >>= 1) { s1 += __shfl_down(s1, o, 64); s2 += __shfl_down(s2, o, 64); }
  if ((t & 63) == 0) { r1[t >> 6] = s1; r2[t >> 6] = s2; }
  __syncthreads();
  if (t == 0) {
    const float a = r1[0] + r1[1] + r1[2] + r1[3];
    const float b = r2[0] + r2[1] + r2[2] + r2[3];
    *lam = expf(a) - expf(b) + LAMBDA_INIT_F;
  }
}

// d = softmax(a1 + rvec1) - lam*softmax(a2 + rvec2); rvec indexed by column j (bias rank-1 term)
__global__ __launch_bounds__(256) void k_softmax(const float* __restrict__ a1, const float* __restrict__ a2,
                                                 const float* __restrict__ lamp, const float* __restrict__ rvec,
                                                 ushort* __restrict__ dm) {
  __shared__ float red[4];
  const size_t row = blockIdx.x;
  const int jb = ((int)row >> 9) << 9;   // b*512
  const float* p1 = a1 + row * 512;
  const float* p2 = a2 + row * 512;
  const int t = threadIdx.x;
  const float v1a = p1[t] + rvec[jb + t],        v1b = p1[t + 256] + rvec[jb + t + 256];
  const float v2a = p2[t] + rvec[8192 + jb + t], v2b = p2[t + 256] + rvec[8192 + jb + t + 256];
  const float m1 = block_max(fmaxf(v1a, v1b), red);
  const float m2 = block_max(fmaxf(v2a, v2b), red);
  const float e1a = expf(v1a - m1), e1b = expf(v1b - m1);
  const float e2a = expf(v2a - m2), e2b = expf(v2b - m2);
  const float s1 = block_sum(e1a + e1b, red);
  const float s2 = block_sum(e2a + e2b, red);
  const float i1 = 1.f / s1, i2 = (*lamp) / s2;
  ushort* o = dm + row * 512;
  o[t]       = f2b(e1a * i1 - e2a * i2);
  o[t + 256] = f2b(e1b * i1 - e2b * i2);
}

__global__ __launch_bounds__(256) void k_postattn(const ushort* __restrict__ P, const ushort* __restrict__ xT,
                                                  const float* __restrict__ norm_w, const float* __restrict__ ln_ff_w,
                                                  ushort* __restrict__ attn, ushort* __restrict__ h) {
  __shared__ float red[4];
  const size_t row = blockIdx.x;
  const ushort* p = P + row * S_;
  const int t = threadIdx.x;
  float v[8]; float ss = 0.f;
#pragma unroll
  for (int i = 0; i < 8; ++i) { v[i] = b2f(p[t + 256 * i]); ss += v[i] * v[i]; }
  ss = block_sum(ss, red);
  const float inv = rsqrtf(ss * (1.f / S_) + 1e-8f);
  const ushort* xr = xT + row * S_;
  ushort* ar = attn + row * S_;
  float x2[8]; float ss2 = 0.f;
#pragma unroll
  for (int i = 0; i < 8; ++i) {
    const int s = t + 256 * i;
    const float at = v[i] * inv * norm_w[s] * ONE_M_LI_F;
    ar[s] = f2b(at);
    const float xx = b2f(xr[s]) + at;
    x2[i] = xx; ss2 += xx * xx;
  }
  ss2 = block_sum(ss2, red);
  const float inv2 = rsqrtf(ss2 * (1.f / S_) + 1e-8f);
  ushort* hr = h + row * S_;
#pragma unroll
  for (int i = 0; i < 8; ++i) { const int s = t + 256 * i; hr[s] = f2b(x2[i] * inv2 * ln_ff_w[s]); }
}

// out[b,s,c] = x[b,s,c] + sumT[b,c,s]
__global__ __launch_bounds__(256) void k_final2(const float* __restrict__ x, const ushort* __restrict__ sumT,
                                                float* __restrict__ out) {
  __shared__ float tile[32][33];
  const int s0 = blockIdx.x * 32, c0 = blockIdx.y * 32, b = blockIdx.z;
  const int tx = threadIdx.x, ty = threadIdx.y;
#pragma unroll
  for (int r = 0; r < 4; ++r) {
    const int c = ty + 8 * r;
    tile[c][tx] = b2f(sumT[((size_t)b * C_ + c0 + c) * S_ + s0 + tx]);
  }
  __syncthreads();
#pragma unroll
  for (int r = 0; r < 4; ++r) {
    const int s = ty + 8 * r;
    const size_t o = ((size_t)b * S_ + s0 + s) * C_ + c0 + tx;
    out[o] = x[o] + tile[tx][s];
  }
}

__global__ void k_probe(float* out, float v) { out[0] = v; }

// ---------------- launch ----------------
extern "C" void kernel_launch(void* const* d_in, const int* in_sizes, int n_in,
                              void* d_out, int out_size, void* d_ws, size_t ws_size,
                              hipStream_t stream) {
  const float* x       = (const float*)d_in[0];
  const float* ln_attn = (const float*)d_in[1];
  const float* q12_w   = (const float*)d_in[2];
  const float* q12_b   = (const float*)d_in[3];
  const float* k12_w   = (const float*)d_in[4];
  const float* k12_b   = (const float*)d_in[5];
  const float* v_w     = (const float*)d_in[6];
  const float* v_b     = (const float*)d_in[7];
  const float* lq1     = (const float*)d_in[8];
  const float* lk1     = (const float*)d_in[9];
  const float* lq2     = (const float*)d_in[10];
  const float* lk2     = (const float*)d_in[11];
  const float* norm_w  = (const float*)d_in[12];
  const float* ln_ff   = (const float*)d_in[13];
  const float* ff_w1   = (const float*)d_in[14];
  const float* ff_b1   = (const float*)d_in[15];
  const float* ff_w2   = (const float*)d_in[16];
  const float* ff_b2   = (const float*)d_in[17];
  float* out = (float*)d_out;

  if (ws_size < 184844544ull) {
    k_probe<<<1, 1, 0, stream>>>(out, (float)(ws_size >> 20));
    return;
  }

  char* ws = (char*)d_ws;
  ushort* slotA = (ushort*)(ws + 0);
  ushort* slotB = (ushort*)(ws + 33554432);
  ushort* slotC = (ushort*)(ws + 67108864);
  ushort* slotD = (ushort*)(ws + 100663296);
  ushort* slotE = (ushort*)(ws + 134217728);
  ushort* slotF = (ushort*)(ws + 167772160);
  float*  part  = (float*) (ws + 184549376);
  float*  rms1  = (float*) (ws + 184811520);
  float*  lamp  = (float*) (ws + 184844288);

  // liveness-packed aliases
  ushort* aT   = slotA;                          // trans_norm .. decomp2 (+V-direct)
  ushort* k12c = slotA;                          // convert .. M12T
  ushort* T12s = slotA;                          // T1 / T2 (33.5 MB)
  ushort* hbuf = slotA;                          // postattn .. FFN1
  ushort* trT  = slotB;                          // decomp2 .. T2-proj
  ushort* Pm   = slotB;                          // PV out
  ushort* ff1T = slotB;
  ushort* seT  = slotC;                          // decomp2 .. a2 (+gemv)
  ushort* attn = slotC;
  ushort* VT   = slotD;                          // V-direct .. PV
  ushort* ff2T = slotD;
  ushort* xT   = slotE;                          // trans_norm .. postattn
  ushort* ffo  = slotE;
  ushort* wsl  = slotF;                          // vwT, then q12c
  ushort* q12c = slotF;
  ushort* dmat = slotF;                          // softmax out (8.4 MB)
  float*  vvb  = (float*)(ws + 167772160 + 12582912);  // F+12MB: vv[4096]
  float*  rvec = vvb + 4096;                           // rvec[16384]
  ushort* M12T = (ushort*)d_out;                 // [4096,2048] bf16 (16.78 MB)
  float*  scr  = (float*)((char*)d_out + 16777216);    // [2][16][512][512] f32 (33.5 MB)
  ushort* H1   = (ushort*)d_out;                 // FFN half (67 MB; M12T/scr dead)

  const dim3 blk256(256), blk512(512), blkT(32, 8);

  // seq-axis rmsnorm + transpose
  k_rms_part<<<dim3(2, 8, B_), blk256, 0, stream>>>(x, part);
  k_rms_fin<<<dim3(32), blk256, 0, stream>>>(part, rms1);
  k_trans_norm<<<dim3(64, 16, B_), blkT, 0, stream>>>(x, rms1, ln_attn, aT, xT);

  // V path, direct-transposed: VT[b][s][c] = sum_k v_w[k,s]*aT[b*512+c,k] + v_b[s]
  k_wtrans<<<dim3(64, 64), blkT, 0, stream>>>(v_w, wsl, 2048, 2048, 0);
  gemm_nt<5><<<dim3(16, 4, 16), blk256, 0, stream>>>(wsl, aT, VT, 2048, 2048, 2048, 512,
                                                     0, 1048576, 1048576, 0, 0, 1.f, v_b);

  // decompose (fused trend+seasonal)
  k_decomp2<<<dim3(65536), blk256, 0, stream>>>(aT, trT, seT);
  k_lambda<<<dim3(1), blk256, 0, stream>>>(lq1, lk1, lq2, lk2, lamp);

  // weight products: M12T[h][n][k] = sum_t q_hw[k,t]*k_hw[n,t]  (h = half)
  k_convert<<<dim3(4096), blk256, 0, stream>>>(q12_w, q12c);
  k_convert<<<dim3(4096), blk256, 0, stream>>>(k12_w, k12c);
  gemm_nt<3><<<dim3(16, 16, 2), blk256, 0, stream>>>(k12c, q12c, M12T, 2048, 4096, 4096, 2048,
                                                     2048, 2048, 4194304, 0, 0, 1.f, nullptr);

  // bias rank-1 term: vv = k_hw . q_hb ; rvec = SCALE * Se . vv
  k_matvec<<<dim3(2048), blk256, 0, stream>>>(k12_w, q12_b, vvb);
  k_gemv<<<dim3(8192), blk256, 0, stream>>>(seT, vvb, rvec);

  // T1 = Tr.M1 -> a1 ; T2 = Tr.M2 -> a2   (a_h = T_h.Se^T * SCALE)
  gemm256<3><<<dim3(32, 8), blk512, 0, stream>>>(trT, M12T, T12s, nullptr, nullptr,
                                                 2048, 2048, 2048, 2048);
  gemm_nt<0><<<dim3(4, 4, 16), blk256, 0, stream>>>(T12s, seT, scr, 2048, 2048, 2048, 512,
                                                    1048576, 1048576, 262144, 0, 0, SCALE_F, nullptr);
  gemm256<3><<<dim3(32, 8), blk512, 0, stream>>>(trT, M12T + 4194304, T12s, nullptr, nullptr,
                                                 2048, 2048, 2048, 2048);
  gemm_nt<0><<<dim3(4, 4, 16), blk256, 0, stream>>>(T12s, seT, scr + 4194304, 2048, 2048, 2048, 512,
                                                    1048576, 1048576, 262144, 0, 0, SCALE_F, nullptr);

  // softmax -> dmat, PV -> Pm
  k_softmax<<<dim3(8192), blk256, 0, stream>>>(scr, scr + 4194304, lamp, rvec, dmat);
  gemm_nt<3><<<dim3(4, 16, B_), blk256, 0, stream>>>(dmat, VT, Pm, 512, 512, 512, 2048,
                                                     262144, 1048576, 1048576, 0, 0, 1.f, nullptr);

  // post-attn fused norms: attn->C, hbuf->A
  k_postattn<<<dim3(8192), blk256, 0, stream>>>(Pm, xT, norm_w, ln_ff, attn, hbuf);

  // FFN weights: ff1T->B, ff2T->D
  k_wtrans<<<dim3(64, 256), blkT, 0, stream>>>(ff_w1, ff1T, 2048, 8192, 0);
  k_wtrans<<<dim3(256, 64), blkT, 0, stream>>>(ff_w2, ff2T, 8192, 2048, 0);

  // FFN in 2 N-halves of H, full M=8192 each
  gemm256<2><<<dim3(32, 16), blk512, 0, stream>>>(hbuf, ff1T, H1, ff_b1, nullptr,
                                                  2048, 2048, 2048, 4096);
  gemm256<3><<<dim3(32, 8), blk512, 0, stream>>>(H1, ff2T, ffo, nullptr, nullptr,
                                                 4096, 4096, 8192, 2048);
  gemm256<2><<<dim3(32, 16), blk512, 0, stream>>>(hbuf, ff1T + (size_t)4096 * 2048, H1,
                                                  ff_b1 + 4096, nullptr, 2048, 2048, 2048, 4096);
  gemm256<4><<<dim3(32, 8), blk512, 0, stream>>>(H1, ff2T + 4096, ffo, ff_b2, attn,
                                                 4096, 4096, 8192, 2048);

  // out = x + (attn + ffo)^T
  k_final2<<<dim3(64, 16, B_), blkT, 0, stream>>>(x, ffo, out);
}